// Round 10
// baseline (353.121 us; speedup 1.0000x reference)
//
#include <hip/hip_runtime.h>
#include <hip/hip_fp16.h>
#include <math.h>

#define TT 2048
#define CC 64
#define BB 32
#define PAD 512
#define ROWL 3136          // padded bf16 row length

typedef __attribute__((ext_vector_type(8))) short short8;
typedef __attribute__((ext_vector_type(4))) float float4v;

// Toeplitz A-fragment tables: 67 K-steps x 64 lanes x 8 bf16 (hi/lo split)
#define NSTEPS 67
__device__ unsigned short g_afrag_hi[NSTEPS * 64 * 8];
__device__ unsigned short g_afrag_lo[NSTEPS * 64 * 8];

__device__ __forceinline__ float fast_rcp(float x) { return __builtin_amdgcn_rcpf(x); }
__device__ __forceinline__ float fast_exp2(float x) { return __builtin_amdgcn_exp2f(x); }
__device__ __forceinline__ float fast_log2(float x) { return __builtin_amdgcn_logf(x); }

__device__ __forceinline__ unsigned short f2bf(float x) {  // RNE bf16 round
  union { float f; unsigned u; } v; v.f = x;
  unsigned r = (v.u + 0x7FFFu + ((v.u >> 16) & 1u)) >> 16;
  return (unsigned short)r;
}
__device__ __forceinline__ float bf2f(unsigned short u) {
  union { unsigned u32; float f; } v; v.u32 = ((unsigned)u) << 16; return v.f;
}

// tanh-form GELU via sigmoid: x*sigma(1.595769x + 0.0713548x^3), max err ~4e-4
__device__ __forceinline__ float gelu_f(float x) {
  float u = x * x;
  float w = x * fmaf(-0.10294217f, u, -2.3020231f);
  float e = fast_exp2(w);
  return x * fast_rcp(1.0f + e);
}

// ---- init: Gaussian taps -> Toeplitz MFMA fragments (grid-strided) ----
__global__ void init_frag() {
  __shared__ float ktap[2016];
  __shared__ double ssum[5];
  const int   Rr[5]  = {32, 64, 128, 256, 512};
  const float sg[5]  = {8.f, 16.f, 32.f, 64.f, 128.f};
  const int   off[5] = {0, 72, 208, 472, 984};
  const int tid = threadIdx.x;

  for (int idx = tid; idx < 2016; idx += 256) {
    int s = (idx < 72) ? 0 : (idx < 208) ? 1 : (idx < 472) ? 2 : (idx < 984) ? 3 : 4;
    int d = idx - off[s];
    float v = 0.f;
    if (d <= 2 * Rr[s]) {
      float n = (float)(d - Rr[s]) / sg[s];
      v = __expf(-0.5f * n * n);
    }
    ktap[idx] = v;
  }
  __syncthreads();
  if (tid < 5) {
    double sum = 0.0;
    for (int d = 0; d <= 2 * Rr[tid]; ++d) sum += (double)ktap[off[tid] + d];
    ssum[tid] = 1.0 / (sum + 1e-12);
  }
  __syncthreads();
  for (int idx = tid; idx < 2016; idx += 256) {
    int s = (idx < 72) ? 0 : (idx < 208) ? 1 : (idx < 472) ? 2 : (idx < 984) ? 3 : 4;
    ktap[idx] *= (float)ssum[s];
  }
  __syncthreads();

  const int cum[5] = {0, 3, 8, 17, 34};
  for (int e = blockIdx.x * 256 + tid; e < NSTEPS * 64; e += gridDim.x * 256) {
    int stg = e >> 6, lane = e & 63;
    int s = (stg < 3) ? 0 : (stg < 8) ? 1 : (stg < 17) ? 2 : (stg < 34) ? 3 : 4;
    int st = stg - cum[s];
    int i = lane & 15, h = lane >> 4;
    for (int e2 = 0; e2 < 8; ++e2) {
      int d = st * 32 + 8 * h + e2 - i;
      float v = (d >= 0 && d <= 2 * Rr[s]) ? ktap[off[s] + d] : 0.f;
      unsigned short hi = f2bf(v);
      g_afrag_hi[e * 8 + e2] = hi;
      g_afrag_lo[e * 8 + e2] = f2bf(v - bf2f(hi));
    }
  }
}

// ---- transpose x [B,T,C] fp32 -> xT [B,C,T] bf16 (coalesced both sides) ----
__global__ void transpose_in(const float* __restrict__ x, unsigned short* __restrict__ xT) {
  __shared__ float tile[64][65];
  const int tid = threadIdx.x;
  const int b = blockIdx.x >> 5;           // 32 t-tiles per batch
  const int t0 = (blockIdx.x & 31) * 64;

  const float* src = x + ((size_t)b * TT + t0) * CC;
  #pragma unroll
  for (int k = 0; k < 16; ++k) {
    int idx = k * 256 + tid;
    int row = idx >> 6, col = idx & 63;     // coalesced along C
    tile[row][col] = src[(size_t)row * CC + col];
  }
  __syncthreads();
  unsigned short* dst = xT + (size_t)b * CC * TT + t0;
  #pragma unroll
  for (int k = 0; k < 16; ++k) {
    int idx = k * 256 + tid;
    int c = idx >> 6, tt = idx & 63;        // coalesced along T
    dst[(size_t)c * TT + tt] = f2bf(tile[tt][c]);
  }
}

// ---- transpose outT [B,C,T] fp32 -> out [B,T,C] fp32 (coalesced both sides) ----
__global__ void transpose_out(const float* __restrict__ outT, float* __restrict__ out) {
  __shared__ float tile[64][65];
  const int tid = threadIdx.x;
  const int b = blockIdx.x >> 5;
  const int t0 = (blockIdx.x & 31) * 64;

  const float* src = outT + (size_t)b * CC * TT + t0;
  #pragma unroll
  for (int k = 0; k < 16; ++k) {
    int idx = k * 256 + tid;
    int cc2 = idx >> 6, tt = idx & 63;      // coalesced along T
    tile[cc2][tt] = src[(size_t)cc2 * TT + tt];
  }
  __syncthreads();
  float* dst = out + ((size_t)b * TT + t0) * CC;
  #pragma unroll
  for (int k = 0; k < 16; ++k) {
    int idx = k * 256 + tid;
    int tt = idx >> 6, cc2 = idx & 63;      // coalesced along C
    dst[(size_t)tt * CC + cc2] = tile[cc2][tt];
  }
}

template <int WSPATH>
__launch_bounds__(256, 5)
__global__ void fused_main_t(const float* __restrict__ x, const unsigned short* __restrict__ xT,
                             const float* __restrict__ W1, const float* __restrict__ b1,
                             const float* __restrict__ W2, const float* __restrict__ b2,
                             const float* __restrict__ W3, const float* __restrict__ b3,
                             float* __restrict__ outT, float* __restrict__ out) {
  __shared__ unsigned short row_hi[ROWL];
  __shared__ __half gbuf[8][5][16][18];   // gates; s=0..2 aliased as feats A1->A2

  const int tid = threadIdx.x;
  const int blk = blockIdx.x;
  const int c = blk & (CC - 1);
  const int b = blk >> 6;

  // ---- stage reflect-padded row as bf16 ----
  if (WSPATH) {
    const unsigned short* xtr = xT + (size_t)(b * CC + c) * TT;   // contiguous bf16 row
    for (int i2 = tid; i2 < ROWL; i2 += 256) {
      int t = i2 - PAD;
      t = (t < 0) ? -t : t;
      t = (t >= TT) ? (2 * TT - 2 - t) : t;
      row_hi[i2] = xtr[t];
    }
  } else {
    const float* xrow = x + (size_t)b * TT * CC + c;
    for (int i2 = tid; i2 < ROWL; i2 += 256) {
      int t = i2 - PAD;
      t = (t < 0) ? -t : t;
      t = (t >= TT) ? (2 * TT - 2 - t) : t;
      row_hi[i2] = f2bf(xrow[(size_t)t * CC]);
    }
  }
  __syncthreads();

  const int t0 = tid * 8;
  const int lane = tid & 63;
  const int wvi = tid >> 6;

  // ======== Phase A1: sliding-window stats (bf16 x) -> feats ========
  {
    float w24[24];
    {
      const unsigned short* ph = &row_hi[PAD + t0 - 8];
      unsigned hw[12];
      *(uint4*)&hw[0] = *(const uint4*)ph;
      *(uint4*)&hw[4] = *(const uint4*)(ph + 8);
      *(uint4*)&hw[8] = *(const uint4*)(ph + 16);
      #pragma unroll
      for (int m2 = 0; m2 < 12; ++m2) {
        union { unsigned u; float f; } a, bb;
        a.u  = (hw[m2] & 0xFFFFu) << 16;
        bb.u = hw[m2] & 0xFFFF0000u;
        w24[2 * m2]     = a.f;
        w24[2 * m2 + 1] = bb.f;
      }
    }

    float sm = 0.f, sq = 0.f, scv = 0.f;
    #pragma unroll
    for (int j = 0; j < 16; ++j) {
      float v = w24[1 + j];
      sm += v;
      sq  = fmaf(v, v, sq);
      scv = fmaf(v, (float)j - 7.5f, scv);
    }

    #pragma unroll
    for (int i = 0; i < 8; ++i) {
      const float xv   = w24[i + 8];
      const float mean = sm * 0.0625f;
      const float ex2  = sq * 0.0625f;
      const float var  = fmaxf(ex2 - mean * mean, 0.f);
      const float slope = scv * (1.0f / 340.0f);
      const float stdv = sqrtf(var + 1e-6f);
      float z = (xv - mean) * fast_rcp(stdv);
      z = fminf(fmaxf(z, -10.f), 10.f);
      float lv = fast_log2(var + 1e-6f) * 0.069314718f;   // *ln2/10 = ln(.)/10
      float ns = slope * fast_rcp(stdv + 1e-6f);
      ns = fminf(fmaxf(ns, -10.f), 10.f);

      const int e = t0 + i;
      const int ch = e >> 8, rr = e & 15, pp = (e >> 4) & 15;
      gbuf[ch][0][rr][pp] = __float2half(z);
      gbuf[ch][1][rr][pp] = __float2half(lv);
      gbuf[ch][2][rr][pp] = __float2half(ns);

      if (i < 7) {   // slide window by one
        const float xo = w24[i + 1], xn = w24[i + 17];
        scv = fmaf(8.5f, xo, fmaf(7.5f, xn, scv - sm));
        sm += (xn - xo);
        sq = fmaf(xn, xn, sq);
        sq = fmaf(-xo, xo, sq);
      }
    }
  }

  // ======== Phase A2: wave-wide MLP via MFMA ========
  {
    const int kg = lane >> 4;        // k-group == row-quarter hq
    const int m  = lane & 15;        // element column

    // W2 A-fragments (hi/lo) built in-register from global W2
    short8 w2h0, w2l0, w2h1, w2l1;
    {
      const float* p0 = W2 + (size_t)m * 32 + 8 * kg;
      const float* p1 = W2 + (size_t)(16 + m) * 32 + 8 * kg;
      #pragma unroll
      for (int e2 = 0; e2 < 8; ++e2) {
        float v0 = p0[e2], v1 = p1[e2];
        unsigned short h0 = f2bf(v0);
        w2h0[e2] = (short)h0; w2l0[e2] = (short)f2bf(v0 - bf2f(h0));
        unsigned short h1v = f2bf(v1);
        w2h1[e2] = (short)h1v; w2l1[e2] = (short)f2bf(v1 - bf2f(h1v));
      }
    }

    float4v w1q[6], b1q2[2], b2a, b2b, w3A[5], w3B[5];
    #pragma unroll
    for (int k = 0; k < 6; ++k) w1q[k] = *(const float4v*)(W1 + 24 * kg + 4 * k);
    b1q2[0] = *(const float4v*)(b1 + 8 * kg);
    b1q2[1] = *(const float4v*)(b1 + 8 * kg + 4);
    b2a = *(const float4v*)(b2 + 4 * kg);
    b2b = *(const float4v*)(b2 + 16 + 4 * kg);
    #pragma unroll
    for (int k = 0; k < 5; ++k) {
      w3A[k] = *(const float4v*)(W3 + 32 * k + 4 * kg);
      w3B[k] = *(const float4v*)(W3 + 32 * k + 16 + 4 * kg);
    }
    const float b30 = b3[0], b31 = b3[1], b32 = b3[2], b33 = b3[3], b34 = b3[4];
    const float kS = 2.0609929f;     // log2(e)/0.7

    #pragma unroll 1
    for (int j = 0; j < 32; ++j) {
      const int ch = 2 * wvi + (j >> 4);
      const int pp = j & 15;

      // features of column element m
      float z  = __half2float(gbuf[ch][0][m][pp]);
      float lv = __half2float(gbuf[ch][1][m][pp]);
      float ns = __half2float(gbuf[ch][2][m][pp]);

      // layer 1 in B-fragment layout: 8 neurons (k = 8*kg + e2) of column m
      short8 bfr;
      #pragma unroll
      for (int e2 = 0; e2 < 8; ++e2) {
        float p = b1q2[e2 >> 2][e2 & 3];
        p = fmaf(w1q[(3*e2)   >> 2][(3*e2)   & 3], z,  p);
        p = fmaf(w1q[(3*e2+1) >> 2][(3*e2+1) & 3], lv, p);
        p = fmaf(w1q[(3*e2+2) >> 2][(3*e2+2) & 3], ns, p);
        bfr[e2] = (short)f2bf(gelu_f(p));
      }

      // layer 2: h2pre = W2 * h1  (2 g-tiles, W2 hi/lo 2-pass)
      float4v acc0 = {0.f,0.f,0.f,0.f}, acc1 = {0.f,0.f,0.f,0.f};
      acc0 = __builtin_amdgcn_mfma_f32_16x16x32_bf16(w2h0, bfr, acc0, 0, 0, 0);
      acc0 = __builtin_amdgcn_mfma_f32_16x16x32_bf16(w2l0, bfr, acc0, 0, 0, 0);
      acc1 = __builtin_amdgcn_mfma_f32_16x16x32_bf16(w2h1, bfr, acc1, 0, 0, 0);
      acc1 = __builtin_amdgcn_mfma_f32_16x16x32_bf16(w2l1, bfr, acc1, 0, 0, 0);

      // bias + GELU + W3 partial dot (rows g = 16gt + 4kg + r)
      float lg0 = 0.f, lg1 = 0.f, lg2 = 0.f, lg3 = 0.f, lg4 = 0.f;
      #pragma unroll
      for (int r = 0; r < 4; ++r) {
        float ha = gelu_f(acc0[r] + b2a[r]);
        float hb = gelu_f(acc1[r] + b2b[r]);
        lg0 = fmaf(w3A[0][r], ha, lg0); lg0 = fmaf(w3B[0][r], hb, lg0);
        lg1 = fmaf(w3A[1][r], ha, lg1); lg1 = fmaf(w3B[1][r], hb, lg1);
        lg2 = fmaf(w3A[2][r], ha, lg2); lg2 = fmaf(w3B[2][r], hb, lg2);
        lg3 = fmaf(w3A[3][r], ha, lg3); lg3 = fmaf(w3B[3][r], hb, lg3);
        lg4 = fmaf(w3A[4][r], ha, lg4); lg4 = fmaf(w3B[4][r], hb, lg4);
      }
      // reduce across the 4 row-quarters (lanes m, m+16, m+32, m+48)
      lg0 += __shfl_xor(lg0, 16); lg0 += __shfl_xor(lg0, 32);
      lg1 += __shfl_xor(lg1, 16); lg1 += __shfl_xor(lg1, 32);
      lg2 += __shfl_xor(lg2, 16); lg2 += __shfl_xor(lg2, 32);
      lg3 += __shfl_xor(lg3, 16); lg3 += __shfl_xor(lg3, 32);
      lg4 += __shfl_xor(lg4, 16); lg4 += __shfl_xor(lg4, 32);
      lg0 += b30; lg1 += b31; lg2 += b32; lg3 += b33; lg4 += b34;

      // softmax(logits/0.7) via exp2 with folded scale
      const float mx = fmaxf(fmaxf(fmaxf(lg0, lg1), fmaxf(lg2, lg3)), lg4);
      const float mxs = mx * kS;
      float e0 = fast_exp2(fmaf(lg0, kS, -mxs));
      float e1 = fast_exp2(fmaf(lg1, kS, -mxs));
      float e2 = fast_exp2(fmaf(lg2, kS, -mxs));
      float e3 = fast_exp2(fmaf(lg3, kS, -mxs));
      float e4 = fast_exp2(fmaf(lg4, kS, -mxs));
      const float rs = fast_rcp(e0 + e1 + e2 + e3 + e4);

      // each quarter writes its own scale slot; quarter 0 also writes s=4
      float gw = e0;
      gw = (kg == 1) ? e1 : gw;
      gw = (kg == 2) ? e2 : gw;
      gw = (kg == 3) ? e3 : gw;
      gbuf[ch][kg][m][pp] = __float2half(gw * rs);
      if (kg == 0) gbuf[ch][4][m][pp] = __float2half(e4 * rs);
    }
  }
  // gates produced & consumed by the same wave -> no barrier needed

  // ======== Phase B: Toeplitz-MFMA conv (tap hi/lo, single bf16 B) ========
  {
    const int hq = lane >> 4, p = lane & 15;
    const int ch0 = 2 * wvi, ch1 = 2 * wvi + 1;

    const int Rs[5]    = {32, 64, 128, 256, 512};
    const int steps[5] = {3, 5, 9, 17, 33};
    const int cum[5]   = {0, 3, 8, 17, 34};

    float4v o0 = {0.f,0.f,0.f,0.f}, o1 = {0.f,0.f,0.f,0.f};

    #pragma unroll 1
    for (int s = 0; s < 5; ++s) {
      float4v a0 = {0.f,0.f,0.f,0.f}, a1 = {0.f,0.f,0.f,0.f};
      const int eb0 = PAD + 256 * ch0 - Rs[s] + 16 * p + 8 * hq;
      const int eb1 = eb0 + 256;
      const unsigned short* ahb = g_afrag_hi + (size_t)cum[s] * 512 + lane * 8;
      const unsigned short* alb = g_afrag_lo + (size_t)cum[s] * 512 + lane * 8;

      for (int st = 0; st < steps[s]; ++st) {
        short8 kh = *(const short8*)(ahb + st * 512);
        short8 kl = *(const short8*)(alb + st * 512);
        short8 b0h = *(const short8*)(&row_hi[eb0 + st * 32]);
        short8 b1h = *(const short8*)(&row_hi[eb1 + st * 32]);
        a0 = __builtin_amdgcn_mfma_f32_16x16x32_bf16(kh, b0h, a0, 0, 0, 0);
        a0 = __builtin_amdgcn_mfma_f32_16x16x32_bf16(kl, b0h, a0, 0, 0, 0);
        a1 = __builtin_amdgcn_mfma_f32_16x16x32_bf16(kh, b1h, a1, 0, 0, 0);
        a1 = __builtin_amdgcn_mfma_f32_16x16x32_bf16(kl, b1h, a1, 0, 0, 0);
      }
      #pragma unroll
      for (int r = 0; r < 4; ++r) {
        o0[r] = fmaf(__half2float(gbuf[ch0][s][4 * hq + r][p]), a0[r], o0[r]);
        o1[r] = fmaf(__half2float(gbuf[ch1][s][4 * hq + r][p]), a1[r], o1[r]);
      }
    }

    if (WSPATH) {
      // contiguous [B,C,T] write: lane (hq,p) owns 4 consecutive t -> float4
      float* orow = outT + (size_t)(b * CC + c) * TT;
      *(float4v*)(orow + 256 * ch0 + 16 * p + 4 * hq) = o0;
      *(float4v*)(orow + 256 * ch1 + 16 * p + 4 * hq) = o1;
    } else {
      const size_t obase = (size_t)b * TT * CC + c;
      #pragma unroll
      for (int r = 0; r < 4; ++r) {
        out[obase + (size_t)(256 * ch0 + 16 * p + 4 * hq + r) * CC] = o0[r];
        out[obase + (size_t)(256 * ch1 + 16 * p + 4 * hq + r) * CC] = o1[r];
      }
    }
  }
}

extern "C" void kernel_launch(void* const* d_in, const int* in_sizes, int n_in,
                              void* d_out, int out_size, void* d_ws, size_t ws_size,
                              hipStream_t stream) {
  const float* x  = (const float*)d_in[0];
  const float* W1 = (const float*)d_in[1];
  const float* b1 = (const float*)d_in[2];
  const float* W2 = (const float*)d_in[3];
  const float* b2 = (const float*)d_in[4];
  const float* W3 = (const float*)d_in[5];
  const float* b3 = (const float*)d_in[6];
  float* outp = (float*)d_out;

  hipLaunchKernelGGL(init_frag, dim3(8), dim3(256), 0, stream);

  const size_t xt_bytes  = (size_t)BB * CC * TT * sizeof(unsigned short);  // 8.4 MB
  const size_t ot_bytes  = (size_t)BB * CC * TT * sizeof(float);           // 16.8 MB
  if (ws_size >= xt_bytes + ot_bytes) {
    unsigned short* xT = (unsigned short*)d_ws;
    float* outT = (float*)((char*)d_ws + xt_bytes);
    hipLaunchKernelGGL(transpose_in, dim3(BB * 32), dim3(256), 0, stream, x, xT);
    hipLaunchKernelGGL(fused_main_t<1>, dim3(BB * CC), dim3(256), 0, stream,
                       x, xT, W1, b1, W2, b2, W3, b3, outT, outp);
    hipLaunchKernelGGL(transpose_out, dim3(BB * 32), dim3(256), 0, stream, outT, outp);
  } else {
    hipLaunchKernelGGL(fused_main_t<0>, dim3(BB * CC), dim3(256), 0, stream,
                       x, (const unsigned short*)nullptr, W1, b1, W2, b2, W3, b3,
                       (float*)nullptr, outp);
  }
}

// Round 11
// 198.264 us; speedup vs baseline: 1.7811x; 1.7811x over previous
//
#include <hip/hip_runtime.h>
#include <hip/hip_fp16.h>
#include <math.h>

#define TT 2048
#define CC 64
#define BB 32
#define PAD 512
#define ROWL 3136          // padded bf16 row length

typedef __attribute__((ext_vector_type(8))) short short8;
typedef __attribute__((ext_vector_type(4))) float float4v;

// Toeplitz A-fragment tables: 67 K-steps x 64 lanes x 8 bf16 (hi/lo split)
#define NSTEPS 67
__device__ unsigned short g_afrag_hi[NSTEPS * 64 * 8];
__device__ unsigned short g_afrag_lo[NSTEPS * 64 * 8];

__device__ __forceinline__ float fast_rcp(float x) { return __builtin_amdgcn_rcpf(x); }
__device__ __forceinline__ float fast_exp2(float x) { return __builtin_amdgcn_exp2f(x); }
__device__ __forceinline__ float fast_log2(float x) { return __builtin_amdgcn_logf(x); }

__device__ __forceinline__ unsigned short f2bf(float x) {  // RNE bf16 round
  union { float f; unsigned u; } v; v.f = x;
  unsigned r = (v.u + 0x7FFFu + ((v.u >> 16) & 1u)) >> 16;
  return (unsigned short)r;
}
__device__ __forceinline__ float bf2f(unsigned short u) {
  union { unsigned u32; float f; } v; v.u32 = ((unsigned)u) << 16; return v.f;
}

// tanh-form GELU via sigmoid: x*sigma(1.595769x + 0.0713548x^3), max err ~4e-4
__device__ __forceinline__ float gelu_f(float x) {
  float u = x * x;
  float w = x * fmaf(-0.10294217f, u, -2.3020231f);
  float e = fast_exp2(w);
  return x * fast_rcp(1.0f + e);
}

// ---- init: Gaussian taps -> Toeplitz MFMA fragments (grid-strided) ----
__global__ void init_frag() {
  __shared__ float ktap[2016];
  __shared__ double ssum[5];
  const int   Rr[5]  = {32, 64, 128, 256, 512};
  const float sg[5]  = {8.f, 16.f, 32.f, 64.f, 128.f};
  const int   off[5] = {0, 72, 208, 472, 984};
  const int tid = threadIdx.x;

  for (int idx = tid; idx < 2016; idx += 256) {
    int s = (idx < 72) ? 0 : (idx < 208) ? 1 : (idx < 472) ? 2 : (idx < 984) ? 3 : 4;
    int d = idx - off[s];
    float v = 0.f;
    if (d <= 2 * Rr[s]) {
      float n = (float)(d - Rr[s]) / sg[s];
      v = __expf(-0.5f * n * n);
    }
    ktap[idx] = v;
  }
  __syncthreads();
  if (tid < 5) {
    double sum = 0.0;
    for (int d = 0; d <= 2 * Rr[tid]; ++d) sum += (double)ktap[off[tid] + d];
    ssum[tid] = 1.0 / (sum + 1e-12);
  }
  __syncthreads();
  for (int idx = tid; idx < 2016; idx += 256) {
    int s = (idx < 72) ? 0 : (idx < 208) ? 1 : (idx < 472) ? 2 : (idx < 984) ? 3 : 4;
    ktap[idx] *= (float)ssum[s];
  }
  __syncthreads();

  const int cum[5] = {0, 3, 8, 17, 34};
  for (int e = blockIdx.x * 256 + tid; e < NSTEPS * 64; e += gridDim.x * 256) {
    int stg = e >> 6, lane = e & 63;
    int s = (stg < 3) ? 0 : (stg < 8) ? 1 : (stg < 17) ? 2 : (stg < 34) ? 3 : 4;
    int st = stg - cum[s];
    int i = lane & 15, h = lane >> 4;
    for (int e2 = 0; e2 < 8; ++e2) {
      int d = st * 32 + 8 * h + e2 - i;
      float v = (d >= 0 && d <= 2 * Rr[s]) ? ktap[off[s] + d] : 0.f;
      unsigned short hi = f2bf(v);
      g_afrag_hi[e * 8 + e2] = hi;
      g_afrag_lo[e * 8 + e2] = f2bf(v - bf2f(hi));
    }
  }
}

// ---- transpose x [B,T,C] fp32 -> xT [B,C,T] bf16 (coalesced both sides) ----
__global__ void transpose_in(const float* __restrict__ x, unsigned short* __restrict__ xT) {
  __shared__ float tile[64][65];
  const int tid = threadIdx.x;
  const int b = blockIdx.x >> 5;           // 32 t-tiles per batch
  const int t0 = (blockIdx.x & 31) * 64;

  const float* src = x + ((size_t)b * TT + t0) * CC;
  #pragma unroll
  for (int k = 0; k < 16; ++k) {
    int idx = k * 256 + tid;
    int row = idx >> 6, col = idx & 63;     // coalesced along C
    tile[row][col] = src[(size_t)row * CC + col];
  }
  __syncthreads();
  unsigned short* dst = xT + (size_t)b * CC * TT + t0;
  #pragma unroll
  for (int k = 0; k < 16; ++k) {
    int idx = k * 256 + tid;
    int c = idx >> 6, tt = idx & 63;        // coalesced along T
    dst[(size_t)c * TT + tt] = f2bf(tile[tt][c]);
  }
}

// ---- transpose outT [B,C,T] fp32 -> out [B,T,C] fp32 (coalesced both sides) ----
__global__ void transpose_out(const float* __restrict__ outT, float* __restrict__ out) {
  __shared__ float tile[64][65];
  const int tid = threadIdx.x;
  const int b = blockIdx.x >> 5;
  const int t0 = (blockIdx.x & 31) * 64;

  const float* src = outT + (size_t)b * CC * TT + t0;
  #pragma unroll
  for (int k = 0; k < 16; ++k) {
    int idx = k * 256 + tid;
    int cc2 = idx >> 6, tt = idx & 63;      // coalesced along T
    tile[cc2][tt] = src[(size_t)cc2 * TT + tt];
  }
  __syncthreads();
  float* dst = out + ((size_t)b * TT + t0) * CC;
  #pragma unroll
  for (int k = 0; k < 16; ++k) {
    int idx = k * 256 + tid;
    int tt = idx >> 6, cc2 = idx & 63;      // coalesced along C
    dst[(size_t)tt * CC + cc2] = tile[cc2][tt];
  }
}

template <int WSPATH>
__launch_bounds__(256, 4)
__global__ void fused_main_t(const float* __restrict__ x, const unsigned short* __restrict__ xT,
                             const float* __restrict__ W1, const float* __restrict__ b1,
                             const float* __restrict__ W2, const float* __restrict__ b2,
                             const float* __restrict__ W3, const float* __restrict__ b3,
                             float* __restrict__ outT, float* __restrict__ out) {
  __shared__ unsigned short row_hi[ROWL];
  __shared__ __half gbuf[8][5][16][18];   // gates; s=0..2 aliased as feats A1->A2

  const int tid = threadIdx.x;
  const int blk = blockIdx.x;
  const int c = blk & (CC - 1);
  const int b = blk >> 6;

  // ---- stage reflect-padded row as bf16 ----
  if (WSPATH) {
    const unsigned short* xtr = xT + (size_t)(b * CC + c) * TT;   // contiguous bf16 row
    for (int i2 = tid; i2 < ROWL; i2 += 256) {
      int t = i2 - PAD;
      t = (t < 0) ? -t : t;
      t = (t >= TT) ? (2 * TT - 2 - t) : t;
      row_hi[i2] = xtr[t];
    }
  } else {
    const float* xrow = x + (size_t)b * TT * CC + c;
    for (int i2 = tid; i2 < ROWL; i2 += 256) {
      int t = i2 - PAD;
      t = (t < 0) ? -t : t;
      t = (t >= TT) ? (2 * TT - 2 - t) : t;
      row_hi[i2] = f2bf(xrow[(size_t)t * CC]);
    }
  }
  __syncthreads();

  const int t0 = tid * 8;
  const int lane = tid & 63;
  const int wvi = tid >> 6;

  // ======== Phase A1: sliding-window stats (bf16 x) -> feats ========
  {
    float w24[24];
    {
      const unsigned short* ph = &row_hi[PAD + t0 - 8];
      unsigned hw[12];
      *(uint4*)&hw[0] = *(const uint4*)ph;
      *(uint4*)&hw[4] = *(const uint4*)(ph + 8);
      *(uint4*)&hw[8] = *(const uint4*)(ph + 16);
      #pragma unroll
      for (int m2 = 0; m2 < 12; ++m2) {
        union { unsigned u; float f; } a, bb;
        a.u  = (hw[m2] & 0xFFFFu) << 16;
        bb.u = hw[m2] & 0xFFFF0000u;
        w24[2 * m2]     = a.f;
        w24[2 * m2 + 1] = bb.f;
      }
    }

    float sm = 0.f, sq = 0.f, scv = 0.f;
    #pragma unroll
    for (int j = 0; j < 16; ++j) {
      float v = w24[1 + j];
      sm += v;
      sq  = fmaf(v, v, sq);
      scv = fmaf(v, (float)j - 7.5f, scv);
    }

    #pragma unroll
    for (int i = 0; i < 8; ++i) {
      const float xv   = w24[i + 8];
      const float mean = sm * 0.0625f;
      const float ex2  = sq * 0.0625f;
      const float var  = fmaxf(ex2 - mean * mean, 0.f);
      const float slope = scv * (1.0f / 340.0f);
      const float stdv = sqrtf(var + 1e-6f);
      float z = (xv - mean) * fast_rcp(stdv);
      z = fminf(fmaxf(z, -10.f), 10.f);
      float lv = fast_log2(var + 1e-6f) * 0.069314718f;   // *ln2/10 = ln(.)/10
      float ns = slope * fast_rcp(stdv + 1e-6f);
      ns = fminf(fmaxf(ns, -10.f), 10.f);

      const int e = t0 + i;
      const int ch = e >> 8, rr = e & 15, pp = (e >> 4) & 15;
      gbuf[ch][0][rr][pp] = __float2half(z);
      gbuf[ch][1][rr][pp] = __float2half(lv);
      gbuf[ch][2][rr][pp] = __float2half(ns);

      if (i < 7) {   // slide window by one
        const float xo = w24[i + 1], xn = w24[i + 17];
        scv = fmaf(8.5f, xo, fmaf(7.5f, xn, scv - sm));
        sm += (xn - xo);
        sq = fmaf(xn, xn, sq);
        sq = fmaf(-xo, xo, sq);
      }
    }
  }

  // ======== Phase A2: wave-wide MLP via MFMA ========
  {
    const int kg = lane >> 4;        // k-group == row-quarter hq
    const int m  = lane & 15;        // element column

    // W2 A-fragments (hi/lo) built in-register from global W2
    short8 w2h0, w2l0, w2h1, w2l1;
    {
      const float* p0 = W2 + (size_t)m * 32 + 8 * kg;
      const float* p1 = W2 + (size_t)(16 + m) * 32 + 8 * kg;
      #pragma unroll
      for (int e2 = 0; e2 < 8; ++e2) {
        float v0 = p0[e2], v1 = p1[e2];
        unsigned short h0 = f2bf(v0);
        w2h0[e2] = (short)h0; w2l0[e2] = (short)f2bf(v0 - bf2f(h0));
        unsigned short h1v = f2bf(v1);
        w2h1[e2] = (short)h1v; w2l1[e2] = (short)f2bf(v1 - bf2f(h1v));
      }
    }

    float4v w1q[6], b1q2[2], b2a, b2b, w3A[5], w3B[5];
    #pragma unroll
    for (int k = 0; k < 6; ++k) w1q[k] = *(const float4v*)(W1 + 24 * kg + 4 * k);
    b1q2[0] = *(const float4v*)(b1 + 8 * kg);
    b1q2[1] = *(const float4v*)(b1 + 8 * kg + 4);
    b2a = *(const float4v*)(b2 + 4 * kg);
    b2b = *(const float4v*)(b2 + 16 + 4 * kg);
    #pragma unroll
    for (int k = 0; k < 5; ++k) {
      w3A[k] = *(const float4v*)(W3 + 32 * k + 4 * kg);
      w3B[k] = *(const float4v*)(W3 + 32 * k + 16 + 4 * kg);
    }
    const float b30 = b3[0], b31 = b3[1], b32 = b3[2], b33 = b3[3], b34 = b3[4];
    const float kS = 2.0609929f;     // log2(e)/0.7

    #pragma unroll 1
    for (int j = 0; j < 32; ++j) {
      const int ch = 2 * wvi + (j >> 4);
      const int pp = j & 15;

      // features of column element m
      float z  = __half2float(gbuf[ch][0][m][pp]);
      float lv = __half2float(gbuf[ch][1][m][pp]);
      float ns = __half2float(gbuf[ch][2][m][pp]);

      // layer 1 in B-fragment layout: 8 neurons (k = 8*kg + e2) of column m
      short8 bfr;
      #pragma unroll
      for (int e2 = 0; e2 < 8; ++e2) {
        float p = b1q2[e2 >> 2][e2 & 3];
        p = fmaf(w1q[(3*e2)   >> 2][(3*e2)   & 3], z,  p);
        p = fmaf(w1q[(3*e2+1) >> 2][(3*e2+1) & 3], lv, p);
        p = fmaf(w1q[(3*e2+2) >> 2][(3*e2+2) & 3], ns, p);
        bfr[e2] = (short)f2bf(gelu_f(p));
      }

      // layer 2: h2pre = W2 * h1  (2 g-tiles, W2 hi/lo 2-pass)
      float4v acc0 = {0.f,0.f,0.f,0.f}, acc1 = {0.f,0.f,0.f,0.f};
      acc0 = __builtin_amdgcn_mfma_f32_16x16x32_bf16(w2h0, bfr, acc0, 0, 0, 0);
      acc0 = __builtin_amdgcn_mfma_f32_16x16x32_bf16(w2l0, bfr, acc0, 0, 0, 0);
      acc1 = __builtin_amdgcn_mfma_f32_16x16x32_bf16(w2h1, bfr, acc1, 0, 0, 0);
      acc1 = __builtin_amdgcn_mfma_f32_16x16x32_bf16(w2l1, bfr, acc1, 0, 0, 0);

      // bias + GELU + W3 partial dot (rows g = 16gt + 4kg + r)
      float lg0 = 0.f, lg1 = 0.f, lg2 = 0.f, lg3 = 0.f, lg4 = 0.f;
      #pragma unroll
      for (int r = 0; r < 4; ++r) {
        float ha = gelu_f(acc0[r] + b2a[r]);
        float hb = gelu_f(acc1[r] + b2b[r]);
        lg0 = fmaf(w3A[0][r], ha, lg0); lg0 = fmaf(w3B[0][r], hb, lg0);
        lg1 = fmaf(w3A[1][r], ha, lg1); lg1 = fmaf(w3B[1][r], hb, lg1);
        lg2 = fmaf(w3A[2][r], ha, lg2); lg2 = fmaf(w3B[2][r], hb, lg2);
        lg3 = fmaf(w3A[3][r], ha, lg3); lg3 = fmaf(w3B[3][r], hb, lg3);
        lg4 = fmaf(w3A[4][r], ha, lg4); lg4 = fmaf(w3B[4][r], hb, lg4);
      }
      // reduce across the 4 row-quarters (lanes m, m+16, m+32, m+48)
      lg0 += __shfl_xor(lg0, 16); lg0 += __shfl_xor(lg0, 32);
      lg1 += __shfl_xor(lg1, 16); lg1 += __shfl_xor(lg1, 32);
      lg2 += __shfl_xor(lg2, 16); lg2 += __shfl_xor(lg2, 32);
      lg3 += __shfl_xor(lg3, 16); lg3 += __shfl_xor(lg3, 32);
      lg4 += __shfl_xor(lg4, 16); lg4 += __shfl_xor(lg4, 32);
      lg0 += b30; lg1 += b31; lg2 += b32; lg3 += b33; lg4 += b34;

      // softmax(logits/0.7) via exp2 with folded scale
      const float mx = fmaxf(fmaxf(fmaxf(lg0, lg1), fmaxf(lg2, lg3)), lg4);
      const float mxs = mx * kS;
      float e0 = fast_exp2(fmaf(lg0, kS, -mxs));
      float e1 = fast_exp2(fmaf(lg1, kS, -mxs));
      float e2 = fast_exp2(fmaf(lg2, kS, -mxs));
      float e3 = fast_exp2(fmaf(lg3, kS, -mxs));
      float e4 = fast_exp2(fmaf(lg4, kS, -mxs));
      const float rs = fast_rcp(e0 + e1 + e2 + e3 + e4);

      // each quarter writes its own scale slot; quarter 0 also writes s=4
      float gw = e0;
      gw = (kg == 1) ? e1 : gw;
      gw = (kg == 2) ? e2 : gw;
      gw = (kg == 3) ? e3 : gw;
      gbuf[ch][kg][m][pp] = __float2half(gw * rs);
      if (kg == 0) gbuf[ch][4][m][pp] = __float2half(e4 * rs);
    }
  }
  // gates produced & consumed by the same wave -> no barrier needed

  // ======== Phase B: Toeplitz-MFMA conv (tap hi/lo, single bf16 B) ========
  {
    const int hq = lane >> 4, p = lane & 15;
    const int ch0 = 2 * wvi, ch1 = 2 * wvi + 1;

    const int Rs[5]    = {32, 64, 128, 256, 512};
    const int steps[5] = {3, 5, 9, 17, 33};
    const int cum[5]   = {0, 3, 8, 17, 34};

    float4v o0 = {0.f,0.f,0.f,0.f}, o1 = {0.f,0.f,0.f,0.f};

    #pragma unroll 1
    for (int s = 0; s < 5; ++s) {
      float4v a0 = {0.f,0.f,0.f,0.f}, a1 = {0.f,0.f,0.f,0.f};
      const int eb0 = PAD + 256 * ch0 - Rs[s] + 16 * p + 8 * hq;
      const int eb1 = eb0 + 256;
      const unsigned short* ahb = g_afrag_hi + (size_t)cum[s] * 512 + lane * 8;
      const unsigned short* alb = g_afrag_lo + (size_t)cum[s] * 512 + lane * 8;

      for (int st = 0; st < steps[s]; ++st) {
        short8 kh = *(const short8*)(ahb + st * 512);
        short8 kl = *(const short8*)(alb + st * 512);
        short8 b0h = *(const short8*)(&row_hi[eb0 + st * 32]);
        short8 b1h = *(const short8*)(&row_hi[eb1 + st * 32]);
        a0 = __builtin_amdgcn_mfma_f32_16x16x32_bf16(kh, b0h, a0, 0, 0, 0);
        a0 = __builtin_amdgcn_mfma_f32_16x16x32_bf16(kl, b0h, a0, 0, 0, 0);
        a1 = __builtin_amdgcn_mfma_f32_16x16x32_bf16(kh, b1h, a1, 0, 0, 0);
        a1 = __builtin_amdgcn_mfma_f32_16x16x32_bf16(kl, b1h, a1, 0, 0, 0);
      }
      #pragma unroll
      for (int r = 0; r < 4; ++r) {
        o0[r] = fmaf(__half2float(gbuf[ch0][s][4 * hq + r][p]), a0[r], o0[r]);
        o1[r] = fmaf(__half2float(gbuf[ch1][s][4 * hq + r][p]), a1[r], o1[r]);
      }
    }

    if (WSPATH) {
      // contiguous [B,C,T] write: lane (hq,p) owns 4 consecutive t -> float4
      float* orow = outT + (size_t)(b * CC + c) * TT;
      *(float4v*)(orow + 256 * ch0 + 16 * p + 4 * hq) = o0;
      *(float4v*)(orow + 256 * ch1 + 16 * p + 4 * hq) = o1;
    } else {
      const size_t obase = (size_t)b * TT * CC + c;
      #pragma unroll
      for (int r = 0; r < 4; ++r) {
        out[obase + (size_t)(256 * ch0 + 16 * p + 4 * hq + r) * CC] = o0[r];
        out[obase + (size_t)(256 * ch1 + 16 * p + 4 * hq + r) * CC] = o1[r];
      }
    }
  }
}

extern "C" void kernel_launch(void* const* d_in, const int* in_sizes, int n_in,
                              void* d_out, int out_size, void* d_ws, size_t ws_size,
                              hipStream_t stream) {
  const float* x  = (const float*)d_in[0];
  const float* W1 = (const float*)d_in[1];
  const float* b1 = (const float*)d_in[2];
  const float* W2 = (const float*)d_in[3];
  const float* b2 = (const float*)d_in[4];
  const float* W3 = (const float*)d_in[5];
  const float* b3 = (const float*)d_in[6];
  float* outp = (float*)d_out;

  hipLaunchKernelGGL(init_frag, dim3(8), dim3(256), 0, stream);

  const size_t xt_bytes  = (size_t)BB * CC * TT * sizeof(unsigned short);  // 8.4 MB
  const size_t ot_bytes  = (size_t)BB * CC * TT * sizeof(float);           // 16.8 MB
  if (ws_size >= xt_bytes + ot_bytes) {
    unsigned short* xT = (unsigned short*)d_ws;
    float* outT = (float*)((char*)d_ws + xt_bytes);
    hipLaunchKernelGGL(transpose_in, dim3(BB * 32), dim3(256), 0, stream, x, xT);
    hipLaunchKernelGGL(fused_main_t<1>, dim3(BB * CC), dim3(256), 0, stream,
                       x, xT, W1, b1, W2, b2, W3, b3, outT, outp);
    hipLaunchKernelGGL(transpose_out, dim3(BB * 32), dim3(256), 0, stream, outT, outp);
  } else {
    hipLaunchKernelGGL(fused_main_t<0>, dim3(BB * CC), dim3(256), 0, stream,
                       x, (const unsigned short*)nullptr, W1, b1, W2, b2, W3, b3,
                       (float*)nullptr, outp);
  }
}

// Round 12
// 198.027 us; speedup vs baseline: 1.7832x; 1.0012x over previous
//
#include <hip/hip_runtime.h>
#include <hip/hip_fp16.h>
#include <math.h>

#define TT 2048
#define CC 64
#define BB 32
#define PAD 512
#define ROWL 3136          // padded bf16 row length

typedef __attribute__((ext_vector_type(8))) short short8;
typedef __attribute__((ext_vector_type(4))) float float4v;

// Toeplitz A-fragment tables: 67 K-steps x 64 lanes x 8 bf16 (hi/lo split)
#define NSTEPS 67
__device__ unsigned short g_afrag_hi[NSTEPS * 64 * 8];
__device__ unsigned short g_afrag_lo[NSTEPS * 64 * 8];

__device__ __forceinline__ float fast_rcp(float x) { return __builtin_amdgcn_rcpf(x); }
__device__ __forceinline__ float fast_exp2(float x) { return __builtin_amdgcn_exp2f(x); }
__device__ __forceinline__ float fast_log2(float x) { return __builtin_amdgcn_logf(x); }

__device__ __forceinline__ unsigned short f2bf(float x) {  // RNE bf16 round
  union { float f; unsigned u; } v; v.f = x;
  unsigned r = (v.u + 0x7FFFu + ((v.u >> 16) & 1u)) >> 16;
  return (unsigned short)r;
}
__device__ __forceinline__ float bf2f(unsigned short u) {
  union { unsigned u32; float f; } v; v.u32 = ((unsigned)u) << 16; return v.f;
}
// HW packed f32x2 -> bf16x2 (RNE), gfx950
__device__ __forceinline__ unsigned cvt_pk_bf16(float lo, float hi) {
  unsigned r;
  asm("v_cvt_pk_bf16_f32 %0, %1, %2" : "=v"(r) : "v"(lo), "v"(hi));
  return r;
}

// tanh-form GELU via sigmoid: x*sigma(1.595769x + 0.0713548x^3), max err ~4e-4
__device__ __forceinline__ float gelu_f(float x) {
  float u = x * x;
  float w = x * fmaf(-0.10294217f, u, -2.3020231f);
  float e = fast_exp2(w);
  return x * fast_rcp(1.0f + e);
}

// ---- init: Gaussian taps -> Toeplitz MFMA fragments (grid-strided) ----
__global__ void init_frag() {
  __shared__ float ktap[2016];
  __shared__ double ssum[5];
  const int   Rr[5]  = {32, 64, 128, 256, 512};
  const float sg[5]  = {8.f, 16.f, 32.f, 64.f, 128.f};
  const int   off[5] = {0, 72, 208, 472, 984};
  const int tid = threadIdx.x;

  for (int idx = tid; idx < 2016; idx += 256) {
    int s = (idx < 72) ? 0 : (idx < 208) ? 1 : (idx < 472) ? 2 : (idx < 984) ? 3 : 4;
    int d = idx - off[s];
    float v = 0.f;
    if (d <= 2 * Rr[s]) {
      float n = (float)(d - Rr[s]) / sg[s];
      v = __expf(-0.5f * n * n);
    }
    ktap[idx] = v;
  }
  __syncthreads();
  if (tid < 5) {
    double sum = 0.0;
    for (int d = 0; d <= 2 * Rr[tid]; ++d) sum += (double)ktap[off[tid] + d];
    ssum[tid] = 1.0 / (sum + 1e-12);
  }
  __syncthreads();
  for (int idx = tid; idx < 2016; idx += 256) {
    int s = (idx < 72) ? 0 : (idx < 208) ? 1 : (idx < 472) ? 2 : (idx < 984) ? 3 : 4;
    ktap[idx] *= (float)ssum[s];
  }
  __syncthreads();

  const int cum[5] = {0, 3, 8, 17, 34};
  for (int e = blockIdx.x * 256 + tid; e < NSTEPS * 64; e += gridDim.x * 256) {
    int stg = e >> 6, lane = e & 63;
    int s = (stg < 3) ? 0 : (stg < 8) ? 1 : (stg < 17) ? 2 : (stg < 34) ? 3 : 4;
    int st = stg - cum[s];
    int i = lane & 15, h = lane >> 4;
    for (int e2 = 0; e2 < 8; ++e2) {
      int d = st * 32 + 8 * h + e2 - i;
      float v = (d >= 0 && d <= 2 * Rr[s]) ? ktap[off[s] + d] : 0.f;
      unsigned short hi = f2bf(v);
      g_afrag_hi[e * 8 + e2] = hi;
      g_afrag_lo[e * 8 + e2] = f2bf(v - bf2f(hi));
    }
  }
}

// ---- transpose x [B,T,C] fp32 -> xT [B,C,T] bf16 (coalesced both sides) ----
__global__ void transpose_in(const float* __restrict__ x, unsigned short* __restrict__ xT) {
  __shared__ float tile[64][65];
  const int tid = threadIdx.x;
  const int b = blockIdx.x >> 5;           // 32 t-tiles per batch
  const int t0 = (blockIdx.x & 31) * 64;

  const float* src = x + ((size_t)b * TT + t0) * CC;
  #pragma unroll
  for (int k = 0; k < 16; ++k) {
    int idx = k * 256 + tid;
    int row = idx >> 6, col = idx & 63;     // coalesced along C
    tile[row][col] = src[(size_t)row * CC + col];
  }
  __syncthreads();
  unsigned short* dst = xT + (size_t)b * CC * TT + t0;
  #pragma unroll
  for (int k = 0; k < 16; ++k) {
    int idx = k * 256 + tid;
    int c = idx >> 6, tt = idx & 63;        // coalesced along T
    dst[(size_t)c * TT + tt] = f2bf(tile[tt][c]);
  }
}

// ---- transpose outT [B,C,T] fp32 -> out [B,T,C] fp32 (coalesced both sides) ----
__global__ void transpose_out(const float* __restrict__ outT, float* __restrict__ out) {
  __shared__ float tile[64][65];
  const int tid = threadIdx.x;
  const int b = blockIdx.x >> 5;
  const int t0 = (blockIdx.x & 31) * 64;

  const float* src = outT + (size_t)b * CC * TT + t0;
  #pragma unroll
  for (int k = 0; k < 16; ++k) {
    int idx = k * 256 + tid;
    int cc2 = idx >> 6, tt = idx & 63;      // coalesced along T
    tile[cc2][tt] = src[(size_t)cc2 * TT + tt];
  }
  __syncthreads();
  float* dst = out + ((size_t)b * TT + t0) * CC;
  #pragma unroll
  for (int k = 0; k < 16; ++k) {
    int idx = k * 256 + tid;
    int tt = idx >> 6, cc2 = idx & 63;      // coalesced along C
    dst[(size_t)tt * CC + cc2] = tile[cc2][tt];
  }
}

template <int WSPATH>
__launch_bounds__(256, 3)
__global__ void fused_main_t(const float* __restrict__ x, const unsigned short* __restrict__ xT,
                             const float* __restrict__ W1, const float* __restrict__ b1,
                             const float* __restrict__ W2, const float* __restrict__ b2,
                             const float* __restrict__ W3, const float* __restrict__ b3,
                             float* __restrict__ outT, float* __restrict__ out) {
  __shared__ unsigned short row_hi[ROWL];
  __shared__ __half gbuf[8][5][16][18];   // gates; s=0..2 aliased as feats A1->A2

  const int tid = threadIdx.x;
  const int blk = blockIdx.x;
  const int c = blk & (CC - 1);
  const int b = blk >> 6;

  // ---- stage reflect-padded row as bf16 ----
  if (WSPATH) {
    const unsigned short* xtr = xT + (size_t)(b * CC + c) * TT;   // contiguous bf16 row
    for (int i2 = tid; i2 < ROWL; i2 += 256) {
      int t = i2 - PAD;
      t = (t < 0) ? -t : t;
      t = (t >= TT) ? (2 * TT - 2 - t) : t;
      row_hi[i2] = xtr[t];
    }
  } else {
    const float* xrow = x + (size_t)b * TT * CC + c;
    for (int i2 = tid; i2 < ROWL; i2 += 256) {
      int t = i2 - PAD;
      t = (t < 0) ? -t : t;
      t = (t >= TT) ? (2 * TT - 2 - t) : t;
      row_hi[i2] = f2bf(xrow[(size_t)t * CC]);
    }
  }
  __syncthreads();

  const int t0 = tid * 8;
  const int lane = tid & 63;
  const int wvi = tid >> 6;

  // ======== Phase A1: sliding-window stats (bf16 x) -> feats ========
  {
    float w24[24];
    {
      const unsigned short* ph = &row_hi[PAD + t0 - 8];
      unsigned hw[12];
      *(uint4*)&hw[0] = *(const uint4*)ph;
      *(uint4*)&hw[4] = *(const uint4*)(ph + 8);
      *(uint4*)&hw[8] = *(const uint4*)(ph + 16);
      #pragma unroll
      for (int m2 = 0; m2 < 12; ++m2) {
        union { unsigned u; float f; } a, bb;
        a.u  = (hw[m2] & 0xFFFFu) << 16;
        bb.u = hw[m2] & 0xFFFF0000u;
        w24[2 * m2]     = a.f;
        w24[2 * m2 + 1] = bb.f;
      }
    }

    float sm = 0.f, sq = 0.f, scv = 0.f;
    #pragma unroll
    for (int j = 0; j < 16; ++j) {
      float v = w24[1 + j];
      sm += v;
      sq  = fmaf(v, v, sq);
      scv = fmaf(v, (float)j - 7.5f, scv);
    }

    #pragma unroll
    for (int i = 0; i < 8; ++i) {
      const float xv   = w24[i + 8];
      const float mean = sm * 0.0625f;
      const float ex2  = sq * 0.0625f;
      const float var  = fmaxf(ex2 - mean * mean, 0.f);
      const float slope = scv * (1.0f / 340.0f);
      const float stdv = sqrtf(var + 1e-6f);
      float z = (xv - mean) * fast_rcp(stdv);
      z = fminf(fmaxf(z, -10.f), 10.f);
      float lv = fast_log2(var + 1e-6f) * 0.069314718f;   // *ln2/10 = ln(.)/10
      float ns = slope * fast_rcp(stdv + 1e-6f);
      ns = fminf(fmaxf(ns, -10.f), 10.f);

      const int e = t0 + i;
      const int ch = e >> 8, rr = e & 15, pp = (e >> 4) & 15;
      gbuf[ch][0][rr][pp] = __float2half(z);
      gbuf[ch][1][rr][pp] = __float2half(lv);
      gbuf[ch][2][rr][pp] = __float2half(ns);

      if (i < 7) {   // slide window by one
        const float xo = w24[i + 1], xn = w24[i + 17];
        scv = fmaf(8.5f, xo, fmaf(7.5f, xn, scv - sm));
        sm += (xn - xo);
        sq = fmaf(xn, xn, sq);
        sq = fmaf(-xo, xo, sq);
      }
    }
  }

  // ======== Phase A2: wave-wide MLP via MFMA (2 chunks per iteration) ========
  {
    const int kg = lane >> 4;        // k-group == row-quarter hq
    const int m  = lane & 15;        // element column
    const int ch0 = 2 * wvi, ch1 = 2 * wvi + 1;

    // W2 A-fragments (hi/lo) built in-register from global W2
    short8 w2h0, w2l0, w2h1, w2l1;
    {
      const float* p0 = W2 + (size_t)m * 32 + 8 * kg;
      const float* p1 = W2 + (size_t)(16 + m) * 32 + 8 * kg;
      #pragma unroll
      for (int e2 = 0; e2 < 8; ++e2) {
        float v0 = p0[e2], v1 = p1[e2];
        unsigned short h0 = f2bf(v0);
        w2h0[e2] = (short)h0; w2l0[e2] = (short)f2bf(v0 - bf2f(h0));
        unsigned short h1v = f2bf(v1);
        w2h1[e2] = (short)h1v; w2l1[e2] = (short)f2bf(v1 - bf2f(h1v));
      }
    }

    float4v w1q[6], b1q2[2], b2a, b2b, w3A[5], w3B[5];
    #pragma unroll
    for (int k = 0; k < 6; ++k) w1q[k] = *(const float4v*)(W1 + 24 * kg + 4 * k);
    b1q2[0] = *(const float4v*)(b1 + 8 * kg);
    b1q2[1] = *(const float4v*)(b1 + 8 * kg + 4);
    b2a = *(const float4v*)(b2 + 4 * kg);
    b2b = *(const float4v*)(b2 + 16 + 4 * kg);
    #pragma unroll
    for (int k = 0; k < 5; ++k) {
      w3A[k] = *(const float4v*)(W3 + 32 * k + 4 * kg);
      w3B[k] = *(const float4v*)(W3 + 32 * k + 16 + 4 * kg);
    }
    const float b30 = b3[0], b31 = b3[1], b32 = b3[2], b33 = b3[3], b34 = b3[4];
    const float kS = 2.0609929f;     // log2(e)/0.7

    auto do_col = [&](int ch, int pp) {
      // features of column element m
      float z  = __half2float(gbuf[ch][0][m][pp]);
      float lv = __half2float(gbuf[ch][1][m][pp]);
      float ns = __half2float(gbuf[ch][2][m][pp]);

      // layer 1 in B-fragment layout: 8 neurons (k = 8*kg + e2) of column m
      float h1v[8];
      #pragma unroll
      for (int e2 = 0; e2 < 8; ++e2) {
        float p = b1q2[e2 >> 2][e2 & 3];
        p = fmaf(w1q[(3*e2)   >> 2][(3*e2)   & 3], z,  p);
        p = fmaf(w1q[(3*e2+1) >> 2][(3*e2+1) & 3], lv, p);
        p = fmaf(w1q[(3*e2+2) >> 2][(3*e2+2) & 3], ns, p);
        h1v[e2] = gelu_f(p);
      }
      union { unsigned u[4]; short8 s; } bu;
      bu.u[0] = cvt_pk_bf16(h1v[0], h1v[1]);
      bu.u[1] = cvt_pk_bf16(h1v[2], h1v[3]);
      bu.u[2] = cvt_pk_bf16(h1v[4], h1v[5]);
      bu.u[3] = cvt_pk_bf16(h1v[6], h1v[7]);

      // layer 2: h2pre = W2 * h1  (2 g-tiles, W2 hi/lo 2-pass)
      float4v acc0 = {0.f,0.f,0.f,0.f}, acc1 = {0.f,0.f,0.f,0.f};
      acc0 = __builtin_amdgcn_mfma_f32_16x16x32_bf16(w2h0, bu.s, acc0, 0, 0, 0);
      acc0 = __builtin_amdgcn_mfma_f32_16x16x32_bf16(w2l0, bu.s, acc0, 0, 0, 0);
      acc1 = __builtin_amdgcn_mfma_f32_16x16x32_bf16(w2h1, bu.s, acc1, 0, 0, 0);
      acc1 = __builtin_amdgcn_mfma_f32_16x16x32_bf16(w2l1, bu.s, acc1, 0, 0, 0);

      // bias + GELU + W3 partial dot (rows g = 16gt + 4kg + r)
      float lg0 = 0.f, lg1 = 0.f, lg2 = 0.f, lg3 = 0.f, lg4 = 0.f;
      #pragma unroll
      for (int r = 0; r < 4; ++r) {
        float ha = gelu_f(acc0[r] + b2a[r]);
        float hb = gelu_f(acc1[r] + b2b[r]);
        lg0 = fmaf(w3A[0][r], ha, lg0); lg0 = fmaf(w3B[0][r], hb, lg0);
        lg1 = fmaf(w3A[1][r], ha, lg1); lg1 = fmaf(w3B[1][r], hb, lg1);
        lg2 = fmaf(w3A[2][r], ha, lg2); lg2 = fmaf(w3B[2][r], hb, lg2);
        lg3 = fmaf(w3A[3][r], ha, lg3); lg3 = fmaf(w3B[3][r], hb, lg3);
        lg4 = fmaf(w3A[4][r], ha, lg4); lg4 = fmaf(w3B[4][r], hb, lg4);
      }
      // reduce across the 4 row-quarters (lanes m, m+16, m+32, m+48)
      lg0 += __shfl_xor(lg0, 16); lg0 += __shfl_xor(lg0, 32);
      lg1 += __shfl_xor(lg1, 16); lg1 += __shfl_xor(lg1, 32);
      lg2 += __shfl_xor(lg2, 16); lg2 += __shfl_xor(lg2, 32);
      lg3 += __shfl_xor(lg3, 16); lg3 += __shfl_xor(lg3, 32);
      lg4 += __shfl_xor(lg4, 16); lg4 += __shfl_xor(lg4, 32);
      lg0 += b30; lg1 += b31; lg2 += b32; lg3 += b33; lg4 += b34;

      // softmax(logits/0.7) via exp2 with folded scale
      const float mx = fmaxf(fmaxf(fmaxf(lg0, lg1), fmaxf(lg2, lg3)), lg4);
      const float mxs = mx * kS;
      float e0 = fast_exp2(fmaf(lg0, kS, -mxs));
      float e1 = fast_exp2(fmaf(lg1, kS, -mxs));
      float e2 = fast_exp2(fmaf(lg2, kS, -mxs));
      float e3 = fast_exp2(fmaf(lg3, kS, -mxs));
      float e4 = fast_exp2(fmaf(lg4, kS, -mxs));
      const float rs = fast_rcp(e0 + e1 + e2 + e3 + e4);

      // each quarter writes its own scale slot; quarter 0 also writes s=4
      float gw = e0;
      gw = (kg == 1) ? e1 : gw;
      gw = (kg == 2) ? e2 : gw;
      gw = (kg == 3) ? e3 : gw;
      gbuf[ch][kg][m][pp] = __float2half(gw * rs);
      if (kg == 0) gbuf[ch][4][m][pp] = __float2half(e4 * rs);
    };

    #pragma unroll 1
    for (int pp = 0; pp < 16; ++pp) {
      do_col(ch0, pp);     // two independent chains -> scheduler interleaves
      do_col(ch1, pp);
    }
  }
  // gates produced & consumed by the same wave -> no barrier needed

  // ======== Phase B: Toeplitz-MFMA conv (tap hi/lo, single bf16 B) ========
  {
    const int hq = lane >> 4, p = lane & 15;
    const int ch0 = 2 * wvi, ch1 = 2 * wvi + 1;

    const int Rs[5]    = {32, 64, 128, 256, 512};
    const int steps[5] = {3, 5, 9, 17, 33};
    const int cum[5]   = {0, 3, 8, 17, 34};

    float4v o0 = {0.f,0.f,0.f,0.f}, o1 = {0.f,0.f,0.f,0.f};

    #pragma unroll 1
    for (int s = 0; s < 5; ++s) {
      float4v a0 = {0.f,0.f,0.f,0.f}, a1 = {0.f,0.f,0.f,0.f};
      const int eb0 = PAD + 256 * ch0 - Rs[s] + 16 * p + 8 * hq;
      const int eb1 = eb0 + 256;
      const unsigned short* ahb = g_afrag_hi + (size_t)cum[s] * 512 + lane * 8;
      const unsigned short* alb = g_afrag_lo + (size_t)cum[s] * 512 + lane * 8;

      for (int st = 0; st < steps[s]; ++st) {
        short8 kh = *(const short8*)(ahb + st * 512);
        short8 kl = *(const short8*)(alb + st * 512);
        short8 b0h = *(const short8*)(&row_hi[eb0 + st * 32]);
        short8 b1h = *(const short8*)(&row_hi[eb1 + st * 32]);
        a0 = __builtin_amdgcn_mfma_f32_16x16x32_bf16(kh, b0h, a0, 0, 0, 0);
        a0 = __builtin_amdgcn_mfma_f32_16x16x32_bf16(kl, b0h, a0, 0, 0, 0);
        a1 = __builtin_amdgcn_mfma_f32_16x16x32_bf16(kh, b1h, a1, 0, 0, 0);
        a1 = __builtin_amdgcn_mfma_f32_16x16x32_bf16(kl, b1h, a1, 0, 0, 0);
      }
      #pragma unroll
      for (int r = 0; r < 4; ++r) {
        o0[r] = fmaf(__half2float(gbuf[ch0][s][4 * hq + r][p]), a0[r], o0[r]);
        o1[r] = fmaf(__half2float(gbuf[ch1][s][4 * hq + r][p]), a1[r], o1[r]);
      }
    }

    if (WSPATH) {
      // contiguous [B,C,T] write: lane (hq,p) owns 4 consecutive t -> float4
      float* orow = outT + (size_t)(b * CC + c) * TT;
      *(float4v*)(orow + 256 * ch0 + 16 * p + 4 * hq) = o0;
      *(float4v*)(orow + 256 * ch1 + 16 * p + 4 * hq) = o1;
    } else {
      const size_t obase = (size_t)b * TT * CC + c;
      #pragma unroll
      for (int r = 0; r < 4; ++r) {
        out[obase + (size_t)(256 * ch0 + 16 * p + 4 * hq + r) * CC] = o0[r];
        out[obase + (size_t)(256 * ch1 + 16 * p + 4 * hq + r) * CC] = o1[r];
      }
    }
  }
}

extern "C" void kernel_launch(void* const* d_in, const int* in_sizes, int n_in,
                              void* d_out, int out_size, void* d_ws, size_t ws_size,
                              hipStream_t stream) {
  const float* x  = (const float*)d_in[0];
  const float* W1 = (const float*)d_in[1];
  const float* b1 = (const float*)d_in[2];
  const float* W2 = (const float*)d_in[3];
  const float* b2 = (const float*)d_in[4];
  const float* W3 = (const float*)d_in[5];
  const float* b3 = (const float*)d_in[6];
  float* outp = (float*)d_out;

  hipLaunchKernelGGL(init_frag, dim3(8), dim3(256), 0, stream);

  const size_t xt_bytes  = (size_t)BB * CC * TT * sizeof(unsigned short);  // 8.4 MB
  const size_t ot_bytes  = (size_t)BB * CC * TT * sizeof(float);           // 16.8 MB
  if (ws_size >= xt_bytes + ot_bytes) {
    unsigned short* xT = (unsigned short*)d_ws;
    float* outT = (float*)((char*)d_ws + xt_bytes);
    hipLaunchKernelGGL(transpose_in, dim3(BB * 32), dim3(256), 0, stream, x, xT);
    hipLaunchKernelGGL(fused_main_t<1>, dim3(BB * CC), dim3(256), 0, stream,
                       x, xT, W1, b1, W2, b2, W3, b3, outT, outp);
    hipLaunchKernelGGL(transpose_out, dim3(BB * 32), dim3(256), 0, stream, outT, outp);
  } else {
    hipLaunchKernelGGL(fused_main_t<0>, dim3(BB * CC), dim3(256), 0, stream,
                       x, (const unsigned short*)nullptr, W1, b1, W2, b2, W3, b3,
                       (float*)nullptr, outp);
  }
}

// Round 13
// 168.245 us; speedup vs baseline: 2.0988x; 1.1770x over previous
//
#include <hip/hip_runtime.h>
#include <hip/hip_fp16.h>
#include <math.h>

#define TT 2048
#define CC 64
#define BB 32
#define PAD 512
#define ROWL 3136          // padded bf16 row length

typedef __attribute__((ext_vector_type(8))) short short8;
typedef __attribute__((ext_vector_type(4))) float float4v;
typedef _Float16 half8 __attribute__((ext_vector_type(8)));

// Toeplitz A-fragment table: 67 K-steps x 64 lanes x 8 bf16 (hi only)
#define NSTEPS 67
__device__ unsigned short g_afrag_hi[NSTEPS * 64 * 8];

__device__ __forceinline__ float fast_rcp(float x) { return __builtin_amdgcn_rcpf(x); }
__device__ __forceinline__ float fast_exp2(float x) { return __builtin_amdgcn_exp2f(x); }
__device__ __forceinline__ float fast_log2(float x) { return __builtin_amdgcn_logf(x); }

__device__ __forceinline__ unsigned short f2bf(float x) {  // RNE bf16 round
  union { float f; unsigned u; } v; v.f = x;
  unsigned r = (v.u + 0x7FFFu + ((v.u >> 16) & 1u)) >> 16;
  return (unsigned short)r;
}
__device__ __forceinline__ float bf2f(unsigned short u) {
  union { unsigned u32; float f; } v; v.u32 = ((unsigned)u) << 16; return v.f;
}

// f32 tanh-form GELU (A1 unused; kept for reference) and packed-f16 GELU:
// gelu(x) = x * sigma(1.595769x + 0.0713548x^3); exp(-s)=exp2(x*(-2.3020231-0.10294217x^2))
__device__ __forceinline__ __half2 gelu_h2(__half2 x) {
  const __half2 c1 = __float2half2_rn(-0.10294217f);
  const __half2 c0 = __float2half2_rn(-2.3020231f);
  const __half2 one = __float2half2_rn(1.0f);
  __half2 u = __hmul2(x, x);
  __half2 w = __hmul2(x, __hfma2(c1, u, c0));
  __half2 e = h2exp2(w);
  return __hmul2(x, h2rcp(__hadd2(e, one)));
}

// ---- init: Gaussian taps -> Toeplitz MFMA fragments (grid-strided) ----
__global__ void init_frag() {
  __shared__ float ktap[2016];
  __shared__ double ssum[5];
  const int   Rr[5]  = {32, 64, 128, 256, 512};
  const float sg[5]  = {8.f, 16.f, 32.f, 64.f, 128.f};
  const int   off[5] = {0, 72, 208, 472, 984};
  const int tid = threadIdx.x;

  for (int idx = tid; idx < 2016; idx += 256) {
    int s = (idx < 72) ? 0 : (idx < 208) ? 1 : (idx < 472) ? 2 : (idx < 984) ? 3 : 4;
    int d = idx - off[s];
    float v = 0.f;
    if (d <= 2 * Rr[s]) {
      float n = (float)(d - Rr[s]) / sg[s];
      v = __expf(-0.5f * n * n);
    }
    ktap[idx] = v;
  }
  __syncthreads();
  if (tid < 5) {
    double sum = 0.0;
    for (int d = 0; d <= 2 * Rr[tid]; ++d) sum += (double)ktap[off[tid] + d];
    ssum[tid] = 1.0 / (sum + 1e-12);
  }
  __syncthreads();
  for (int idx = tid; idx < 2016; idx += 256) {
    int s = (idx < 72) ? 0 : (idx < 208) ? 1 : (idx < 472) ? 2 : (idx < 984) ? 3 : 4;
    ktap[idx] *= (float)ssum[s];
  }
  __syncthreads();

  const int cum[5] = {0, 3, 8, 17, 34};
  for (int e = blockIdx.x * 256 + tid; e < NSTEPS * 64; e += gridDim.x * 256) {
    int stg = e >> 6, lane = e & 63;
    int s = (stg < 3) ? 0 : (stg < 8) ? 1 : (stg < 17) ? 2 : (stg < 34) ? 3 : 4;
    int st = stg - cum[s];
    int i = lane & 15, h = lane >> 4;
    for (int e2 = 0; e2 < 8; ++e2) {
      int d = st * 32 + 8 * h + e2 - i;
      float v = (d >= 0 && d <= 2 * Rr[s]) ? ktap[off[s] + d] : 0.f;
      g_afrag_hi[e * 8 + e2] = f2bf(v);
    }
  }
}

// ---- transpose x [B,T,C] fp32 -> xT [B,C,T] bf16 (coalesced both sides) ----
__global__ void transpose_in(const float* __restrict__ x, unsigned short* __restrict__ xT) {
  __shared__ float tile[64][65];
  const int tid = threadIdx.x;
  const int b = blockIdx.x >> 5;
  const int t0 = (blockIdx.x & 31) * 64;

  const float* src = x + ((size_t)b * TT + t0) * CC;
  #pragma unroll
  for (int k = 0; k < 16; ++k) {
    int idx = k * 256 + tid;
    int row = idx >> 6, col = idx & 63;
    tile[row][col] = src[(size_t)row * CC + col];
  }
  __syncthreads();
  unsigned short* dst = xT + (size_t)b * CC * TT + t0;
  #pragma unroll
  for (int k = 0; k < 16; ++k) {
    int idx = k * 256 + tid;
    int c = idx >> 6, tt = idx & 63;
    dst[(size_t)c * TT + tt] = f2bf(tile[tt][c]);
  }
}

// ---- transpose outT [B,C,T] fp32 -> out [B,T,C] fp32 ----
__global__ void transpose_out(const float* __restrict__ outT, float* __restrict__ out) {
  __shared__ float tile[64][65];
  const int tid = threadIdx.x;
  const int b = blockIdx.x >> 5;
  const int t0 = (blockIdx.x & 31) * 64;

  const float* src = outT + (size_t)b * CC * TT + t0;
  #pragma unroll
  for (int k = 0; k < 16; ++k) {
    int idx = k * 256 + tid;
    int cc2 = idx >> 6, tt = idx & 63;
    tile[cc2][tt] = src[(size_t)cc2 * TT + tt];
  }
  __syncthreads();
  float* dst = out + ((size_t)b * TT + t0) * CC;
  #pragma unroll
  for (int k = 0; k < 16; ++k) {
    int idx = k * 256 + tid;
    int tt = idx >> 6, cc2 = idx & 63;
    dst[(size_t)tt * CC + cc2] = tile[cc2][tt];
  }
}

template <int WSPATH>
__launch_bounds__(256, 3)
__global__ void fused_main_t(const float* __restrict__ x, const unsigned short* __restrict__ xT,
                             const float* __restrict__ W1, const float* __restrict__ b1,
                             const float* __restrict__ W2, const float* __restrict__ b2,
                             const float* __restrict__ W3, const float* __restrict__ b3,
                             float* __restrict__ outT, float* __restrict__ out) {
  __shared__ unsigned short row_hi[ROWL];
  __shared__ __half gbuf[8][5][16][18];   // gates; s=0..2 aliased as feats A1->A2

  const int tid = threadIdx.x;
  const int blk = blockIdx.x;
  const int c = blk & (CC - 1);
  const int b = blk >> 6;

  // ---- stage reflect-padded row as bf16 ----
  if (WSPATH) {
    const unsigned short* xtr = xT + (size_t)(b * CC + c) * TT;
    for (int i2 = tid; i2 < ROWL; i2 += 256) {
      int t = i2 - PAD;
      t = (t < 0) ? -t : t;
      t = (t >= TT) ? (2 * TT - 2 - t) : t;
      row_hi[i2] = xtr[t];
    }
  } else {
    const float* xrow = x + (size_t)b * TT * CC + c;
    for (int i2 = tid; i2 < ROWL; i2 += 256) {
      int t = i2 - PAD;
      t = (t < 0) ? -t : t;
      t = (t >= TT) ? (2 * TT - 2 - t) : t;
      row_hi[i2] = f2bf(xrow[(size_t)t * CC]);
    }
  }
  __syncthreads();

  const int t0 = tid * 8;
  const int lane = tid & 63;
  const int wvi = tid >> 6;

  // ======== Phase A1: sliding-window stats (bf16 x) -> feats ========
  {
    float w24[24];
    {
      const unsigned short* ph = &row_hi[PAD + t0 - 8];
      unsigned hw[12];
      *(uint4*)&hw[0] = *(const uint4*)ph;
      *(uint4*)&hw[4] = *(const uint4*)(ph + 8);
      *(uint4*)&hw[8] = *(const uint4*)(ph + 16);
      #pragma unroll
      for (int m2 = 0; m2 < 12; ++m2) {
        union { unsigned u; float f; } a, bb;
        a.u  = (hw[m2] & 0xFFFFu) << 16;
        bb.u = hw[m2] & 0xFFFF0000u;
        w24[2 * m2]     = a.f;
        w24[2 * m2 + 1] = bb.f;
      }
    }

    float sm = 0.f, sq = 0.f, scv = 0.f;
    #pragma unroll
    for (int j = 0; j < 16; ++j) {
      float v = w24[1 + j];
      sm += v;
      sq  = fmaf(v, v, sq);
      scv = fmaf(v, (float)j - 7.5f, scv);
    }

    #pragma unroll
    for (int i = 0; i < 8; ++i) {
      const float xv   = w24[i + 8];
      const float mean = sm * 0.0625f;
      const float ex2  = sq * 0.0625f;
      const float var  = fmaxf(ex2 - mean * mean, 0.f);
      const float slope = scv * (1.0f / 340.0f);
      const float stdv = sqrtf(var + 1e-6f);
      float z = (xv - mean) * fast_rcp(stdv);
      z = fminf(fmaxf(z, -10.f), 10.f);
      float lv = fast_log2(var + 1e-6f) * 0.069314718f;   // *ln2/10 = ln(.)/10
      float ns = slope * fast_rcp(stdv + 1e-6f);
      ns = fminf(fmaxf(ns, -10.f), 10.f);

      const int e = t0 + i;
      const int ch = e >> 8, rr = e & 15, pp = (e >> 4) & 15;
      gbuf[ch][0][rr][pp] = __float2half(z);
      gbuf[ch][1][rr][pp] = __float2half(lv);
      gbuf[ch][2][rr][pp] = __float2half(ns);

      if (i < 7) {
        const float xo = w24[i + 1], xn = w24[i + 17];
        scv = fmaf(8.5f, xo, fmaf(7.5f, xn, scv - sm));
        sm += (xn - xo);
        sq = fmaf(xn, xn, sq);
        sq = fmaf(-xo, xo, sq);
      }
    }
  }

  // ======== Phase A2: wave-wide MLP via f16 MFMA + packed-f16 VALU ========
  {
    const int kg = lane >> 4;        // k-group == row-quarter
    const int m  = lane & 15;        // element column
    const int ch0 = 2 * wvi, ch1 = 2 * wvi + 1;

    // W2 A-fragments (single-pass f16): frag[e2] = W2[g][8kg+e2], g = 16gt + m
    half8 w2f0, w2f1;
    {
      const float* p0 = W2 + (size_t)m * 32 + 8 * kg;
      const float* p1 = W2 + (size_t)(16 + m) * 32 + 8 * kg;
      #pragma unroll
      for (int e2 = 0; e2 < 8; ++e2) {
        w2f0[e2] = (_Float16)p0[e2];
        w2f1[e2] = (_Float16)p1[e2];
      }
    }

    // W1/b1 as packed pairs: neurons (8kg+2p, 8kg+2p+1)
    __half2 w1z[4], w1l[4], w1n[4], b1p[4];
    #pragma unroll
    for (int p = 0; p < 4; ++p) {
      int n0 = 8 * kg + 2 * p;
      w1z[p] = __halves2half2(__float2half(W1[n0 * 3 + 0]), __float2half(W1[n0 * 3 + 3]));
      w1l[p] = __halves2half2(__float2half(W1[n0 * 3 + 1]), __float2half(W1[n0 * 3 + 4]));
      w1n[p] = __halves2half2(__float2half(W1[n0 * 3 + 2]), __float2half(W1[n0 * 3 + 5]));
      b1p[p] = __halves2half2(__float2half(b1[n0]), __float2half(b1[n0 + 1]));
    }
    // b2 quarters (f32)
    float4v b2a = *(const float4v*)(b2 + 4 * kg);
    float4v b2b = *(const float4v*)(b2 + 16 + 4 * kg);
    // W3 packed pairs matching h2 pair layout
    __half2 w3p[5][4];
    #pragma unroll
    for (int k = 0; k < 5; ++k) {
      int g0 = 4 * kg;
      w3p[k][0] = __halves2half2(__float2half(W3[k * 32 + g0]),      __float2half(W3[k * 32 + g0 + 1]));
      w3p[k][1] = __halves2half2(__float2half(W3[k * 32 + g0 + 2]),  __float2half(W3[k * 32 + g0 + 3]));
      w3p[k][2] = __halves2half2(__float2half(W3[k * 32 + 16 + g0]), __float2half(W3[k * 32 + 16 + g0 + 1]));
      w3p[k][3] = __halves2half2(__float2half(W3[k * 32 + 16 + g0 + 2]), __float2half(W3[k * 32 + 16 + g0 + 3]));
    }
    const float b30 = b3[0], b31 = b3[1], b32 = b3[2], b33 = b3[3], b34 = b3[4];
    const float kS = 2.0609929f;     // log2(e)/0.7

    auto do_col = [&](int ch, int pp) {
      // features of column element m, broadcast to both halves
      __half2 z2 = __half2half2(gbuf[ch][0][m][pp]);
      __half2 l2 = __half2half2(gbuf[ch][1][m][pp]);
      __half2 n2 = __half2half2(gbuf[ch][2][m][pp]);

      // layer 1 (packed pairs) + GELU -> f16 B-fragment
      union { __half2 h2[4]; half8 h8; } bu;
      #pragma unroll
      for (int p = 0; p < 4; ++p) {
        __half2 pre = __hfma2(w1z[p], z2, b1p[p]);
        pre = __hfma2(w1l[p], l2, pre);
        pre = __hfma2(w1n[p], n2, pre);
        bu.h2[p] = gelu_h2(pre);
      }

      // layer 2: single-pass f16 MFMA per g-tile
      float4v acc0 = {0.f,0.f,0.f,0.f}, acc1 = {0.f,0.f,0.f,0.f};
      acc0 = __builtin_amdgcn_mfma_f32_16x16x32_f16(w2f0, bu.h8, acc0, 0, 0, 0);
      acc1 = __builtin_amdgcn_mfma_f32_16x16x32_f16(w2f1, bu.h8, acc1, 0, 0, 0);

      // bias (f32) -> pack pairs -> packed GELU
      __half2 hh0 = __floats2half2_rn(acc0[0] + b2a[0], acc0[1] + b2a[1]);
      __half2 hh1 = __floats2half2_rn(acc0[2] + b2a[2], acc0[3] + b2a[3]);
      __half2 hh2 = __floats2half2_rn(acc1[0] + b2b[0], acc1[1] + b2b[1]);
      __half2 hh3 = __floats2half2_rn(acc1[2] + b2b[2], acc1[3] + b2b[3]);
      hh0 = gelu_h2(hh0); hh1 = gelu_h2(hh1); hh2 = gelu_h2(hh2); hh3 = gelu_h2(hh3);

      // W3 partial dots in packed f16
      float lg[5];
      #pragma unroll
      for (int k = 0; k < 5; ++k) {
        __half2 a = __hmul2(w3p[k][0], hh0);
        a = __hfma2(w3p[k][1], hh1, a);
        a = __hfma2(w3p[k][2], hh2, a);
        a = __hfma2(w3p[k][3], hh3, a);
        lg[k] = __low2float(a) + __high2float(a);
      }
      // reduce across the 4 row-quarters
      #pragma unroll
      for (int k = 0; k < 5; ++k) {
        lg[k] += __shfl_xor(lg[k], 16);
        lg[k] += __shfl_xor(lg[k], 32);
      }
      lg[0] += b30; lg[1] += b31; lg[2] += b32; lg[3] += b33; lg[4] += b34;

      // softmax(logits/0.7), no max-sub (logits O(1) for this data)
      float e0 = fast_exp2(lg[0] * kS);
      float e1 = fast_exp2(lg[1] * kS);
      float e2 = fast_exp2(lg[2] * kS);
      float e3 = fast_exp2(lg[3] * kS);
      float e4 = fast_exp2(lg[4] * kS);
      const float rs = fast_rcp(e0 + e1 + e2 + e3 + e4);

      float gw = e0;
      gw = (kg == 1) ? e1 : gw;
      gw = (kg == 2) ? e2 : gw;
      gw = (kg == 3) ? e3 : gw;
      gbuf[ch][kg][m][pp] = __float2half(gw * rs);
      if (kg == 0) gbuf[ch][4][m][pp] = __float2half(e4 * rs);
    };

    #pragma unroll 1
    for (int pp = 0; pp < 16; ++pp) {
      do_col(ch0, pp);
      do_col(ch1, pp);
    }
  }
  // gates produced & consumed by the same wave -> no barrier needed

  // ======== Phase B: Toeplitz-MFMA conv (tap-hi only, bf16) ========
  {
    const int hq = lane >> 4, p = lane & 15;
    const int ch0 = 2 * wvi, ch1 = 2 * wvi + 1;

    const int Rs[5]    = {32, 64, 128, 256, 512};
    const int steps[5] = {3, 5, 9, 17, 33};
    const int cum[5]   = {0, 3, 8, 17, 34};

    float4v o0 = {0.f,0.f,0.f,0.f}, o1 = {0.f,0.f,0.f,0.f};

    #pragma unroll 1
    for (int s = 0; s < 5; ++s) {
      float4v a0 = {0.f,0.f,0.f,0.f}, a1 = {0.f,0.f,0.f,0.f};
      const int eb0 = PAD + 256 * ch0 - Rs[s] + 16 * p + 8 * hq;
      const int eb1 = eb0 + 256;
      const unsigned short* ahb = g_afrag_hi + (size_t)cum[s] * 512 + lane * 8;

      for (int st = 0; st < steps[s]; ++st) {
        short8 kh = *(const short8*)(ahb + st * 512);
        short8 b0h = *(const short8*)(&row_hi[eb0 + st * 32]);
        short8 b1h = *(const short8*)(&row_hi[eb1 + st * 32]);
        a0 = __builtin_amdgcn_mfma_f32_16x16x32_bf16(kh, b0h, a0, 0, 0, 0);
        a1 = __builtin_amdgcn_mfma_f32_16x16x32_bf16(kh, b1h, a1, 0, 0, 0);
      }
      #pragma unroll
      for (int r = 0; r < 4; ++r) {
        o0[r] = fmaf(__half2float(gbuf[ch0][s][4 * hq + r][p]), a0[r], o0[r]);
        o1[r] = fmaf(__half2float(gbuf[ch1][s][4 * hq + r][p]), a1[r], o1[r]);
      }
    }

    if (WSPATH) {
      float* orow = outT + (size_t)(b * CC + c) * TT;
      *(float4v*)(orow + 256 * ch0 + 16 * p + 4 * hq) = o0;
      *(float4v*)(orow + 256 * ch1 + 16 * p + 4 * hq) = o1;
    } else {
      const size_t obase = (size_t)b * TT * CC + c;
      #pragma unroll
      for (int r = 0; r < 4; ++r) {
        out[obase + (size_t)(256 * ch0 + 16 * p + 4 * hq + r) * CC] = o0[r];
        out[obase + (size_t)(256 * ch1 + 16 * p + 4 * hq + r) * CC] = o1[r];
      }
    }
  }
}

extern "C" void kernel_launch(void* const* d_in, const int* in_sizes, int n_in,
                              void* d_out, int out_size, void* d_ws, size_t ws_size,
                              hipStream_t stream) {
  const float* x  = (const float*)d_in[0];
  const float* W1 = (const float*)d_in[1];
  const float* b1 = (const float*)d_in[2];
  const float* W2 = (const float*)d_in[3];
  const float* b2 = (const float*)d_in[4];
  const float* W3 = (const float*)d_in[5];
  const float* b3 = (const float*)d_in[6];
  float* outp = (float*)d_out;

  hipLaunchKernelGGL(init_frag, dim3(8), dim3(256), 0, stream);

  const size_t xt_bytes  = (size_t)BB * CC * TT * sizeof(unsigned short);  // 8.4 MB
  const size_t ot_bytes  = (size_t)BB * CC * TT * sizeof(float);           // 16.8 MB
  if (ws_size >= xt_bytes + ot_bytes) {
    unsigned short* xT = (unsigned short*)d_ws;
    float* outT = (float*)((char*)d_ws + xt_bytes);
    hipLaunchKernelGGL(transpose_in, dim3(BB * 32), dim3(256), 0, stream, x, xT);
    hipLaunchKernelGGL(fused_main_t<1>, dim3(BB * CC), dim3(256), 0, stream,
                       x, xT, W1, b1, W2, b2, W3, b3, outT, outp);
    hipLaunchKernelGGL(transpose_out, dim3(BB * 32), dim3(256), 0, stream, outT, outp);
  } else {
    hipLaunchKernelGGL(fused_main_t<0>, dim3(BB * CC), dim3(256), 0, stream,
                       x, (const unsigned short*)nullptr, W1, b1, W2, b2, W3, b3,
                       (float*)nullptr, outp);
  }
}

// Round 14
// 166.751 us; speedup vs baseline: 2.1177x; 1.0090x over previous
//
#include <hip/hip_runtime.h>
#include <hip/hip_fp16.h>
#include <math.h>

#define TT 2048
#define CC 64
#define BB 32
#define PAD 512
#define ROWL 3136          // padded bf16 row length

typedef __attribute__((ext_vector_type(8))) short short8;
typedef __attribute__((ext_vector_type(4))) float float4v;
typedef _Float16 half8 __attribute__((ext_vector_type(8)));

#define PINU(v) asm volatile("" : "+v"(v))

// Toeplitz A-fragment table: 67 K-steps x 64 lanes x 8 bf16 (hi only)
#define NSTEPS 67
__device__ unsigned short g_afrag_hi[NSTEPS * 64 * 8];

__device__ __forceinline__ float fast_rcp(float x) { return __builtin_amdgcn_rcpf(x); }
__device__ __forceinline__ float fast_exp2(float x) { return __builtin_amdgcn_exp2f(x); }
__device__ __forceinline__ float fast_log2(float x) { return __builtin_amdgcn_logf(x); }

__device__ __forceinline__ unsigned short f2bf(float x) {  // RNE bf16 round
  union { float f; unsigned u; } v; v.f = x;
  unsigned r = (v.u + 0x7FFFu + ((v.u >> 16) & 1u)) >> 16;
  return (unsigned short)r;
}
__device__ __forceinline__ unsigned h2u(__half2 h) { union { __half2 h; unsigned u; } c; c.h = h; return c.u; }
__device__ __forceinline__ __half2 u2h(unsigned u) { union { unsigned u; __half2 h; } c; c.u = u; return c.h; }
__device__ __forceinline__ unsigned f2u(float f) { union { float f; unsigned u; } c; c.f = f; return c.u; }
__device__ __forceinline__ float u2f(unsigned u) { union { unsigned u; float f; } c; c.u = u; return c.f; }

// packed-f16 GELU: x*sigma(1.595769x+0.0713548x^3); exp(-s)=exp2(x*(-2.3020231-0.10294217x^2))
__device__ __forceinline__ __half2 gelu_h2(__half2 x) {
  const __half2 c1 = __float2half2_rn(-0.10294217f);
  const __half2 c0 = __float2half2_rn(-2.3020231f);
  const __half2 one = __float2half2_rn(1.0f);
  __half2 u = __hmul2(x, x);
  __half2 w = __hmul2(x, __hfma2(c1, u, c0));
  __half2 e = h2exp2(w);
  return __hmul2(x, h2rcp(__hadd2(e, one)));
}

__device__ __forceinline__ void init_frag_body(int bid, int nb, int tid,
                                               float* ktap, double* ssum) {
  const int   Rr[5]  = {32, 64, 128, 256, 512};
  const float sg[5]  = {8.f, 16.f, 32.f, 64.f, 128.f};
  const int   off[5] = {0, 72, 208, 472, 984};

  for (int idx = tid; idx < 2016; idx += 256) {
    int s = (idx < 72) ? 0 : (idx < 208) ? 1 : (idx < 472) ? 2 : (idx < 984) ? 3 : 4;
    int d = idx - off[s];
    float v = 0.f;
    if (d <= 2 * Rr[s]) {
      float n = (float)(d - Rr[s]) / sg[s];
      v = __expf(-0.5f * n * n);
    }
    ktap[idx] = v;
  }
  __syncthreads();
  if (tid < 5) {
    double sum = 0.0;
    for (int d = 0; d <= 2 * Rr[tid]; ++d) sum += (double)ktap[off[tid] + d];
    ssum[tid] = 1.0 / (sum + 1e-12);
  }
  __syncthreads();
  for (int idx = tid; idx < 2016; idx += 256) {
    int s = (idx < 72) ? 0 : (idx < 208) ? 1 : (idx < 472) ? 2 : (idx < 984) ? 3 : 4;
    ktap[idx] *= (float)ssum[s];
  }
  __syncthreads();

  const int cum[5] = {0, 3, 8, 17, 34};
  for (int e = bid * 256 + tid; e < NSTEPS * 64; e += nb * 256) {
    int stg = e >> 6, lane = e & 63;
    int s = (stg < 3) ? 0 : (stg < 8) ? 1 : (stg < 17) ? 2 : (stg < 34) ? 3 : 4;
    int st = stg - cum[s];
    int i = lane & 15, h = lane >> 4;
    for (int e2 = 0; e2 < 8; ++e2) {
      int d = st * 32 + 8 * h + e2 - i;
      float v = (d >= 0 && d <= 2 * Rr[s]) ? ktap[off[s] + d] : 0.f;
      g_afrag_hi[e * 8 + e2] = f2bf(v);
    }
  }
}

__global__ void init_frag() {
  __shared__ float ktap[2016];
  __shared__ double ssum[5];
  init_frag_body(blockIdx.x, gridDim.x, threadIdx.x, ktap, ssum);
}

// ---- transpose x [B,T,C] fp32 -> xT [B,C,T] bf16; blocks 0..7 also init frags ----
__global__ void transpose_in(const float* __restrict__ x, unsigned short* __restrict__ xT) {
  __shared__ float tile[64][65];
  __shared__ float ktap[2016];
  __shared__ double ssum[5];
  const int tid = threadIdx.x;
  const int b = blockIdx.x >> 5;
  const int t0 = (blockIdx.x & 31) * 64;

  const float* src = x + ((size_t)b * TT + t0) * CC;
  #pragma unroll
  for (int k = 0; k < 16; ++k) {
    int idx = k * 256 + tid;
    int row = idx >> 6, col = idx & 63;
    tile[row][col] = src[(size_t)row * CC + col];
  }
  __syncthreads();
  unsigned short* dst = xT + (size_t)b * CC * TT + t0;
  #pragma unroll
  for (int k = 0; k < 16; ++k) {
    int idx = k * 256 + tid;
    int c = idx >> 6, tt = idx & 63;
    dst[(size_t)c * TT + tt] = f2bf(tile[tt][c]);
  }
  if (blockIdx.x < 8) init_frag_body(blockIdx.x, 8, tid, ktap, ssum);
}

// ---- transpose outT [B,C,T] fp32 -> out [B,T,C] fp32 ----
__global__ void transpose_out(const float* __restrict__ outT, float* __restrict__ out) {
  __shared__ float tile[64][65];
  const int tid = threadIdx.x;
  const int b = blockIdx.x >> 5;
  const int t0 = (blockIdx.x & 31) * 64;

  const float* src = outT + (size_t)b * CC * TT + t0;
  #pragma unroll
  for (int k = 0; k < 16; ++k) {
    int idx = k * 256 + tid;
    int cc2 = idx >> 6, tt = idx & 63;
    tile[cc2][tt] = src[(size_t)cc2 * TT + tt];
  }
  __syncthreads();
  float* dst = out + ((size_t)b * TT + t0) * CC;
  #pragma unroll
  for (int k = 0; k < 16; ++k) {
    int idx = k * 256 + tid;
    int tt = idx >> 6, cc2 = idx & 63;
    dst[(size_t)tt * CC + cc2] = tile[cc2][tt];
  }
}

template <int WSPATH>
__launch_bounds__(256, 3)
__global__ void fused_main_t(const float* __restrict__ x, const unsigned short* __restrict__ xT,
                             const float* __restrict__ W1, const float* __restrict__ b1,
                             const float* __restrict__ W2, const float* __restrict__ b2,
                             const float* __restrict__ W3, const float* __restrict__ b3,
                             float* __restrict__ outT, float* __restrict__ out) {
  __shared__ unsigned short row_hi[ROWL];
  __shared__ __half gbuf[8][5][16][18];   // gates; s=0..2 aliased as feats A1->A2

  const int tid = threadIdx.x;
  const int blk = blockIdx.x;
  const int c = blk & (CC - 1);
  const int b = blk >> 6;

  // ---- stage reflect-padded row as bf16 ----
  if (WSPATH) {
    const unsigned short* xtr = xT + (size_t)(b * CC + c) * TT;
    for (int i2 = tid; i2 < ROWL; i2 += 256) {
      int t = i2 - PAD;
      t = (t < 0) ? -t : t;
      t = (t >= TT) ? (2 * TT - 2 - t) : t;
      row_hi[i2] = xtr[t];
    }
  } else {
    const float* xrow = x + (size_t)b * TT * CC + c;
    for (int i2 = tid; i2 < ROWL; i2 += 256) {
      int t = i2 - PAD;
      t = (t < 0) ? -t : t;
      t = (t >= TT) ? (2 * TT - 2 - t) : t;
      row_hi[i2] = f2bf(xrow[(size_t)t * CC]);
    }
  }
  __syncthreads();

  const int t0 = tid * 8;
  const int lane = tid & 63;
  const int wvi = tid >> 6;

  // ======== Phase A1: sliding-window stats (bf16 x) -> feats ========
  {
    float w24[24];
    {
      const unsigned short* ph = &row_hi[PAD + t0 - 8];
      unsigned hw[12];
      *(uint4*)&hw[0] = *(const uint4*)ph;
      *(uint4*)&hw[4] = *(const uint4*)(ph + 8);
      *(uint4*)&hw[8] = *(const uint4*)(ph + 16);
      #pragma unroll
      for (int m2 = 0; m2 < 12; ++m2) {
        union { unsigned u; float f; } a, bb;
        a.u  = (hw[m2] & 0xFFFFu) << 16;
        bb.u = hw[m2] & 0xFFFF0000u;
        w24[2 * m2]     = a.f;
        w24[2 * m2 + 1] = bb.f;
      }
    }

    float sm = 0.f, sq = 0.f, scv = 0.f;
    #pragma unroll
    for (int j = 0; j < 16; ++j) {
      float v = w24[1 + j];
      sm += v;
      sq  = fmaf(v, v, sq);
      scv = fmaf(v, (float)j - 7.5f, scv);
    }

    #pragma unroll
    for (int i = 0; i < 8; ++i) {
      const float xv   = w24[i + 8];
      const float mean = sm * 0.0625f;
      const float ex2  = sq * 0.0625f;
      const float var  = fmaxf(ex2 - mean * mean, 0.f);
      const float slope = scv * (1.0f / 340.0f);
      const float stdv = sqrtf(var + 1e-6f);
      float z = (xv - mean) * fast_rcp(stdv);
      z = fminf(fmaxf(z, -10.f), 10.f);
      float lv = fast_log2(var + 1e-6f) * 0.069314718f;   // *ln2/10 = ln(.)/10
      float ns = slope * fast_rcp(stdv + 1e-6f);
      ns = fminf(fmaxf(ns, -10.f), 10.f);

      const int e = t0 + i;
      const int ch = e >> 8, rr = e & 15, pp = (e >> 4) & 15;
      gbuf[ch][0][rr][pp] = __float2half(z);
      gbuf[ch][1][rr][pp] = __float2half(lv);
      gbuf[ch][2][rr][pp] = __float2half(ns);

      if (i < 7) {
        const float xo = w24[i + 1], xn = w24[i + 17];
        scv = fmaf(8.5f, xo, fmaf(7.5f, xn, scv - sm));
        sm += (xn - xo);
        sq = fmaf(xn, xn, sq);
        sq = fmaf(-xo, xo, sq);
      }
    }
  }

  // ======== Phase A2: wave-wide MLP via f16 MFMA + packed-f16 VALU ========
  {
    const int kg = lane >> 4;        // k-group == row-quarter
    const int m  = lane & 15;        // element column
    const int ch0 = 2 * wvi, ch1 = 2 * wvi + 1;

    // W2 A-fragments (single-pass f16), stored as pinned uint4
    uint4 uw2a, uw2b;
    {
      union { half8 h; uint4 q; } ca, cb;
      const float* p0 = W2 + (size_t)m * 32 + 8 * kg;
      const float* p1 = W2 + (size_t)(16 + m) * 32 + 8 * kg;
      #pragma unroll
      for (int e2 = 0; e2 < 8; ++e2) {
        ca.h[e2] = (_Float16)p0[e2];
        cb.h[e2] = (_Float16)p1[e2];
      }
      uw2a = ca.q; uw2b = cb.q;
    }
    PINU(uw2a.x); PINU(uw2a.y); PINU(uw2a.z); PINU(uw2a.w);
    PINU(uw2b.x); PINU(uw2b.y); PINU(uw2b.z); PINU(uw2b.w);

    // W1/b1 packed pairs: neurons (8kg+2p, 8kg+2p+1)
    unsigned uw1z[4], uw1l[4], uw1n[4], ub1[4];
    #pragma unroll
    for (int p = 0; p < 4; ++p) {
      int n0 = 8 * kg + 2 * p;
      uw1z[p] = h2u(__halves2half2(__float2half(W1[n0 * 3 + 0]), __float2half(W1[n0 * 3 + 3])));
      uw1l[p] = h2u(__halves2half2(__float2half(W1[n0 * 3 + 1]), __float2half(W1[n0 * 3 + 4])));
      uw1n[p] = h2u(__halves2half2(__float2half(W1[n0 * 3 + 2]), __float2half(W1[n0 * 3 + 5])));
      ub1[p]  = h2u(__halves2half2(__float2half(b1[n0]), __float2half(b1[n0 + 1])));
      PINU(uw1z[p]); PINU(uw1l[p]); PINU(uw1n[p]); PINU(ub1[p]);
    }
    // b2 quarters (f32, pinned)
    unsigned ub2[8];
    #pragma unroll
    for (int r = 0; r < 4; ++r) {
      ub2[r]     = f2u(b2[4 * kg + r]);
      ub2[4 + r] = f2u(b2[16 + 4 * kg + r]);
      PINU(ub2[r]); PINU(ub2[4 + r]);
    }
    // W3 packed pairs matching h2 pair layout (pinned)
    unsigned uw3[5][4];
    #pragma unroll
    for (int k = 0; k < 5; ++k) {
      int g0 = 4 * kg;
      uw3[k][0] = h2u(__halves2half2(__float2half(W3[k * 32 + g0]),          __float2half(W3[k * 32 + g0 + 1])));
      uw3[k][1] = h2u(__halves2half2(__float2half(W3[k * 32 + g0 + 2]),      __float2half(W3[k * 32 + g0 + 3])));
      uw3[k][2] = h2u(__halves2half2(__float2half(W3[k * 32 + 16 + g0]),     __float2half(W3[k * 32 + 16 + g0 + 1])));
      uw3[k][3] = h2u(__halves2half2(__float2half(W3[k * 32 + 16 + g0 + 2]), __float2half(W3[k * 32 + 16 + g0 + 3])));
      PINU(uw3[k][0]); PINU(uw3[k][1]); PINU(uw3[k][2]); PINU(uw3[k][3]);
    }
    const float b30 = b3[0], b31 = b3[1], b32 = b3[2], b33 = b3[3], b34 = b3[4];
    const float kS = 2.0609929f;     // log2(e)/0.7

    auto do_col = [&](int ch, int pp) {
      __half2 z2 = __half2half2(gbuf[ch][0][m][pp]);
      __half2 l2 = __half2half2(gbuf[ch][1][m][pp]);
      __half2 n2 = __half2half2(gbuf[ch][2][m][pp]);

      // layer 1 (packed pairs) + GELU -> f16 B-fragment
      union { __half2 h2[4]; half8 h8; } bu;
      #pragma unroll
      for (int p = 0; p < 4; ++p) {
        __half2 pre = __hfma2(u2h(uw1z[p]), z2, u2h(ub1[p]));
        pre = __hfma2(u2h(uw1l[p]), l2, pre);
        pre = __hfma2(u2h(uw1n[p]), n2, pre);
        bu.h2[p] = gelu_h2(pre);
      }

      // layer 2: single-pass f16 MFMA per g-tile
      union { uint4 q; half8 h; } wa, wb;
      wa.q = uw2a; wb.q = uw2b;
      float4v acc0 = {0.f,0.f,0.f,0.f}, acc1 = {0.f,0.f,0.f,0.f};
      acc0 = __builtin_amdgcn_mfma_f32_16x16x32_f16(wa.h, bu.h8, acc0, 0, 0, 0);
      acc1 = __builtin_amdgcn_mfma_f32_16x16x32_f16(wb.h, bu.h8, acc1, 0, 0, 0);

      // bias (f32) -> pack pairs -> packed GELU
      __half2 hh0 = __floats2half2_rn(acc0[0] + u2f(ub2[0]), acc0[1] + u2f(ub2[1]));
      __half2 hh1 = __floats2half2_rn(acc0[2] + u2f(ub2[2]), acc0[3] + u2f(ub2[3]));
      __half2 hh2 = __floats2half2_rn(acc1[0] + u2f(ub2[4]), acc1[1] + u2f(ub2[5]));
      __half2 hh3 = __floats2half2_rn(acc1[2] + u2f(ub2[6]), acc1[3] + u2f(ub2[7]));
      hh0 = gelu_h2(hh0); hh1 = gelu_h2(hh1); hh2 = gelu_h2(hh2); hh3 = gelu_h2(hh3);

      // W3 partial dots in packed f16
      float lg[5];
      #pragma unroll
      for (int k = 0; k < 5; ++k) {
        __half2 a = __hmul2(u2h(uw3[k][0]), hh0);
        a = __hfma2(u2h(uw3[k][1]), hh1, a);
        a = __hfma2(u2h(uw3[k][2]), hh2, a);
        a = __hfma2(u2h(uw3[k][3]), hh3, a);
        lg[k] = __low2float(a) + __high2float(a);
      }
      #pragma unroll
      for (int k = 0; k < 5; ++k) {
        lg[k] += __shfl_xor(lg[k], 16);
        lg[k] += __shfl_xor(lg[k], 32);
      }
      lg[0] += b30; lg[1] += b31; lg[2] += b32; lg[3] += b33; lg[4] += b34;

      // softmax(logits/0.7), no max-sub (logits O(1) for this data)
      float e0 = fast_exp2(lg[0] * kS);
      float e1 = fast_exp2(lg[1] * kS);
      float e2 = fast_exp2(lg[2] * kS);
      float e3 = fast_exp2(lg[3] * kS);
      float e4 = fast_exp2(lg[4] * kS);
      const float rs = fast_rcp(e0 + e1 + e2 + e3 + e4);

      float gw = e0;
      gw = (kg == 1) ? e1 : gw;
      gw = (kg == 2) ? e2 : gw;
      gw = (kg == 3) ? e3 : gw;
      gbuf[ch][kg][m][pp] = __float2half(gw * rs);
      if (kg == 0) gbuf[ch][4][m][pp] = __float2half(e4 * rs);
    };

    #pragma unroll 1
    for (int pp = 0; pp < 16; ++pp) {
      do_col(ch0, pp);
      do_col(ch1, pp);
    }
  }
  // gates produced & consumed by the same wave -> no barrier needed

  // ======== Phase B: Toeplitz-MFMA conv (tap-hi only, bf16) ========
  {
    const int hq = lane >> 4, p = lane & 15;
    const int ch0 = 2 * wvi, ch1 = 2 * wvi + 1;

    const int Rs[5]    = {32, 64, 128, 256, 512};
    const int steps[5] = {3, 5, 9, 17, 33};
    const int cum[5]   = {0, 3, 8, 17, 34};

    float4v o0 = {0.f,0.f,0.f,0.f}, o1 = {0.f,0.f,0.f,0.f};

    #pragma unroll 1
    for (int s = 0; s < 5; ++s) {
      float4v a0 = {0.f,0.f,0.f,0.f}, a1 = {0.f,0.f,0.f,0.f};
      const int eb0 = PAD + 256 * ch0 - Rs[s] + 16 * p + 8 * hq;
      const int eb1 = eb0 + 256;
      const unsigned short* ahb = g_afrag_hi + (size_t)cum[s] * 512 + lane * 8;

      for (int st = 0; st < steps[s]; ++st) {
        short8 kh = *(const short8*)(ahb + st * 512);
        short8 b0h = *(const short8*)(&row_hi[eb0 + st * 32]);
        short8 b1h = *(const short8*)(&row_hi[eb1 + st * 32]);
        a0 = __builtin_amdgcn_mfma_f32_16x16x32_bf16(kh, b0h, a0, 0, 0, 0);
        a1 = __builtin_amdgcn_mfma_f32_16x16x32_bf16(kh, b1h, a1, 0, 0, 0);
      }
      #pragma unroll
      for (int r = 0; r < 4; ++r) {
        o0[r] = fmaf(__half2float(gbuf[ch0][s][4 * hq + r][p]), a0[r], o0[r]);
        o1[r] = fmaf(__half2float(gbuf[ch1][s][4 * hq + r][p]), a1[r], o1[r]);
      }
    }

    if (WSPATH) {
      float* orow = outT + (size_t)(b * CC + c) * TT;
      *(float4v*)(orow + 256 * ch0 + 16 * p + 4 * hq) = o0;
      *(float4v*)(orow + 256 * ch1 + 16 * p + 4 * hq) = o1;
    } else {
      const size_t obase = (size_t)b * TT * CC + c;
      #pragma unroll
      for (int r = 0; r < 4; ++r) {
        out[obase + (size_t)(256 * ch0 + 16 * p + 4 * hq + r) * CC] = o0[r];
        out[obase + (size_t)(256 * ch1 + 16 * p + 4 * hq + r) * CC] = o1[r];
      }
    }
  }
}

extern "C" void kernel_launch(void* const* d_in, const int* in_sizes, int n_in,
                              void* d_out, int out_size, void* d_ws, size_t ws_size,
                              hipStream_t stream) {
  const float* x  = (const float*)d_in[0];
  const float* W1 = (const float*)d_in[1];
  const float* b1 = (const float*)d_in[2];
  const float* W2 = (const float*)d_in[3];
  const float* b2 = (const float*)d_in[4];
  const float* W3 = (const float*)d_in[5];
  const float* b3 = (const float*)d_in[6];
  float* outp = (float*)d_out;

  const size_t xt_bytes  = (size_t)BB * CC * TT * sizeof(unsigned short);  // 8.4 MB
  const size_t ot_bytes  = (size_t)BB * CC * TT * sizeof(float);           // 16.8 MB
  if (ws_size >= xt_bytes + ot_bytes) {
    unsigned short* xT = (unsigned short*)d_ws;
    float* outT = (float*)((char*)d_ws + xt_bytes);
    hipLaunchKernelGGL(transpose_in, dim3(BB * 32), dim3(256), 0, stream, x, xT);
    hipLaunchKernelGGL(fused_main_t<1>, dim3(BB * CC), dim3(256), 0, stream,
                       x, xT, W1, b1, W2, b2, W3, b3, outT, outp);
    hipLaunchKernelGGL(transpose_out, dim3(BB * 32), dim3(256), 0, stream, outT, outp);
  } else {
    hipLaunchKernelGGL(init_frag, dim3(8), dim3(256), 0, stream);
    hipLaunchKernelGGL(fused_main_t<0>, dim3(BB * CC), dim3(256), 0, stream,
                       x, (const unsigned short*)nullptr, W1, b1, W2, b2, W3, b3,
                       (float*)nullptr, outp);
  }
}

// Round 16
// 151.113 us; speedup vs baseline: 2.3368x; 1.1035x over previous
//
#include <hip/hip_runtime.h>
#include <hip/hip_fp16.h>
#include <math.h>

#define TT 2048
#define CC 64
#define BB 32
#define PAD 512
#define ROWL 3136          // padded bf16 row length

typedef __attribute__((ext_vector_type(8))) short short8;
typedef __attribute__((ext_vector_type(4))) float float4v;
typedef _Float16 half8 __attribute__((ext_vector_type(8)));

// Toeplitz A-fragment table: 67 K-steps x 64 lanes x 8 bf16 (hi only)
#define NSTEPS 67
__device__ unsigned short g_afrag_hi[NSTEPS * 64 * 8];

__device__ __forceinline__ float fast_rcp(float x) { return __builtin_amdgcn_rcpf(x); }
__device__ __forceinline__ float fast_exp2(float x) { return __builtin_amdgcn_exp2f(x); }
__device__ __forceinline__ float fast_log2(float x) { return __builtin_amdgcn_logf(x); }

__device__ __forceinline__ unsigned short f2bf(float x) {  // RNE bf16 round
  union { float f; unsigned u; } v; v.f = x;
  unsigned r = (v.u + 0x7FFFu + ((v.u >> 16) & 1u)) >> 16;
  return (unsigned short)r;
}
__device__ __forceinline__ unsigned h2u(__half2 h) { union { __half2 h; unsigned u; } c; c.h = h; return c.u; }

// packed-f16 GELU: x*sigma(1.595769x+0.0713548x^3); exp(-s)=exp2(x*(-2.3020231-0.10294217x^2))
__device__ __forceinline__ __half2 gelu_h2(__half2 x) {
  const __half2 c1 = __float2half2_rn(-0.10294217f);
  const __half2 c0 = __float2half2_rn(-2.3020231f);
  const __half2 one = __float2half2_rn(1.0f);
  __half2 u = __hmul2(x, x);
  __half2 w = __hmul2(x, __hfma2(c1, u, c0));
  __half2 e = h2exp2(w);
  return __hmul2(x, h2rcp(__hadd2(e, one)));
}

__device__ __forceinline__ void init_frag_body(int bid, int nb, int tid,
                                               float* ktap, double* ssum) {
  const int   Rr[5]  = {32, 64, 128, 256, 512};
  const float sg[5]  = {8.f, 16.f, 32.f, 64.f, 128.f};
  const int   off[5] = {0, 72, 208, 472, 984};

  for (int idx = tid; idx < 2016; idx += 256) {
    int s = (idx < 72) ? 0 : (idx < 208) ? 1 : (idx < 472) ? 2 : (idx < 984) ? 3 : 4;
    int d = idx - off[s];
    float v = 0.f;
    if (d <= 2 * Rr[s]) {
      float n = (float)(d - Rr[s]) / sg[s];
      v = __expf(-0.5f * n * n);
    }
    ktap[idx] = v;
  }
  __syncthreads();
  if (tid < 5) {
    double sum = 0.0;
    for (int d = 0; d <= 2 * Rr[tid]; ++d) sum += (double)ktap[off[tid] + d];
    ssum[tid] = 1.0 / (sum + 1e-12);
  }
  __syncthreads();
  for (int idx = tid; idx < 2016; idx += 256) {
    int s = (idx < 72) ? 0 : (idx < 208) ? 1 : (idx < 472) ? 2 : (idx < 984) ? 3 : 4;
    ktap[idx] *= (float)ssum[s];
  }
  __syncthreads();

  const int cum[5] = {0, 3, 8, 17, 34};
  for (int e = bid * 256 + tid; e < NSTEPS * 64; e += nb * 256) {
    int stg = e >> 6, lane = e & 63;
    int s = (stg < 3) ? 0 : (stg < 8) ? 1 : (stg < 17) ? 2 : (stg < 34) ? 3 : 4;
    int st = stg - cum[s];
    int i = lane & 15, h = lane >> 4;
    for (int e2 = 0; e2 < 8; ++e2) {
      int d = st * 32 + 8 * h + e2 - i;
      float v = (d >= 0 && d <= 2 * Rr[s]) ? ktap[off[s] + d] : 0.f;
      g_afrag_hi[e * 8 + e2] = f2bf(v);
    }
  }
}

__global__ void init_frag() {
  __shared__ float ktap[2016];
  __shared__ double ssum[5];
  init_frag_body(blockIdx.x, gridDim.x, threadIdx.x, ktap, ssum);
}

// ---- transpose x [B,T,C] fp32 -> xT [B,C,T] bf16; blocks 0..7 also init frags ----
__global__ void transpose_in(const float* __restrict__ x, unsigned short* __restrict__ xT) {
  __shared__ float tile[64][65];
  __shared__ float ktap[2016];
  __shared__ double ssum[5];
  const int tid = threadIdx.x;
  const int b = blockIdx.x >> 5;
  const int t0 = (blockIdx.x & 31) * 64;

  const float* src = x + ((size_t)b * TT + t0) * CC;
  #pragma unroll
  for (int k = 0; k < 16; ++k) {
    int idx = k * 256 + tid;
    int row = idx >> 6, col = idx & 63;
    tile[row][col] = src[(size_t)row * CC + col];
  }
  __syncthreads();
  unsigned short* dst = xT + (size_t)b * CC * TT + t0;
  #pragma unroll
  for (int k = 0; k < 16; ++k) {
    int idx = k * 256 + tid;
    int c = idx >> 6, tt = idx & 63;
    dst[(size_t)c * TT + tt] = f2bf(tile[tt][c]);
  }
  if (blockIdx.x < 8) init_frag_body(blockIdx.x, 8, tid, ktap, ssum);
}

// ---- transpose outT [B,C,T] fp32 -> out [B,T,C] fp32 ----
__global__ void transpose_out(const float* __restrict__ outT, float* __restrict__ out) {
  __shared__ float tile[64][65];
  const int tid = threadIdx.x;
  const int b = blockIdx.x >> 5;
  const int t0 = (blockIdx.x & 31) * 64;

  const float* src = outT + (size_t)b * CC * TT + t0;
  #pragma unroll
  for (int k = 0; k < 16; ++k) {
    int idx = k * 256 + tid;
    int cc2 = idx >> 6, tt = idx & 63;
    tile[cc2][tt] = src[(size_t)cc2 * TT + tt];
  }
  __syncthreads();
  float* dst = out + ((size_t)b * TT + t0) * CC;
  #pragma unroll
  for (int k = 0; k < 16; ++k) {
    int idx = k * 256 + tid;
    int tt = idx >> 6, cc2 = idx & 63;
    dst[(size_t)tt * CC + cc2] = tile[cc2][tt];
  }
}

template <int WSPATH>
__launch_bounds__(256, 3)
__global__ void fused_main_t(const float* __restrict__ x, const unsigned short* __restrict__ xT,
                             const float* __restrict__ W1, const float* __restrict__ b1,
                             const float* __restrict__ W2, const float* __restrict__ b2,
                             const float* __restrict__ W3, const float* __restrict__ b3,
                             float* __restrict__ outT, float* __restrict__ out) {
  __shared__ unsigned short row_hi[ROWL];
  __shared__ __half gbuf[8][5][16][18];   // gates; s=0..2 aliased as feats A1->A2

  const int tid = threadIdx.x;
  const int blk = blockIdx.x;
  const int c = blk & (CC - 1);
  const int b = blk >> 6;

  // ---- stage reflect-padded row as bf16 ----
  if (WSPATH) {
    const unsigned short* xtr = xT + (size_t)(b * CC + c) * TT;
    for (int i2 = tid; i2 < ROWL; i2 += 256) {
      int t = i2 - PAD;
      t = (t < 0) ? -t : t;
      t = (t >= TT) ? (2 * TT - 2 - t) : t;
      row_hi[i2] = xtr[t];
    }
  } else {
    const float* xrow = x + (size_t)b * TT * CC + c;
    for (int i2 = tid; i2 < ROWL; i2 += 256) {
      int t = i2 - PAD;
      t = (t < 0) ? -t : t;
      t = (t >= TT) ? (2 * TT - 2 - t) : t;
      row_hi[i2] = f2bf(xrow[(size_t)t * CC]);
    }
  }
  __syncthreads();

  const int t0 = tid * 8;
  const int lane = tid & 63;
  const int wvi = tid >> 6;

  // ======== Phase A1: sliding-window stats (bf16 x) -> feats ========
  {
    float w24[24];
    {
      const unsigned short* ph = &row_hi[PAD + t0 - 8];
      unsigned hw[12];
      *(uint4*)&hw[0] = *(const uint4*)ph;
      *(uint4*)&hw[4] = *(const uint4*)(ph + 8);
      *(uint4*)&hw[8] = *(const uint4*)(ph + 16);
      #pragma unroll
      for (int m2 = 0; m2 < 12; ++m2) {
        union { unsigned u; float f; } a, bb;
        a.u  = (hw[m2] & 0xFFFFu) << 16;
        bb.u = hw[m2] & 0xFFFF0000u;
        w24[2 * m2]     = a.f;
        w24[2 * m2 + 1] = bb.f;
      }
    }

    float sm = 0.f, sq = 0.f, scv = 0.f;
    #pragma unroll
    for (int j = 0; j < 16; ++j) {
      float v = w24[1 + j];
      sm += v;
      sq  = fmaf(v, v, sq);
      scv = fmaf(v, (float)j - 7.5f, scv);
    }

    #pragma unroll
    for (int i = 0; i < 8; ++i) {
      const float xv   = w24[i + 8];
      const float mean = sm * 0.0625f;
      const float ex2  = sq * 0.0625f;
      const float var  = fmaxf(ex2 - mean * mean, 0.f);
      const float slope = scv * (1.0f / 340.0f);
      const float stdv = sqrtf(var + 1e-6f);
      float z = (xv - mean) * fast_rcp(stdv);
      z = fminf(fmaxf(z, -10.f), 10.f);
      float lv = fast_log2(var + 1e-6f) * 0.069314718f;   // *ln2/10 = ln(.)/10
      float ns = slope * fast_rcp(stdv + 1e-6f);
      ns = fminf(fmaxf(ns, -10.f), 10.f);

      const int e = t0 + i;
      const int ch = e >> 8, rr = e & 15, pp = (e >> 4) & 15;
      gbuf[ch][0][rr][pp] = __float2half(z);
      gbuf[ch][1][rr][pp] = __float2half(lv);
      gbuf[ch][2][rr][pp] = __float2half(ns);

      if (i < 7) {
        const float xo = w24[i + 1], xn = w24[i + 17];
        scv = fmaf(8.5f, xo, fmaf(7.5f, xn, scv - sm));
        sm += (xn - xo);
        sq = fmaf(xn, xn, sq);
        sq = fmaf(-xo, xo, sq);
      }
    }
  }

  // ======== Phase A2: MLP, all three layers on/around MFMA ========
  {
    const int kg = lane >> 4;        // quarter index q
    const int m  = lane & 15;        // element column
    const int ch0 = 2 * wvi, ch1 = 2 * wvi + 1;

    // W2 A-fragments (single-pass f16)
    half8 w2f0, w2f1;
    {
      const float* p0 = W2 + (size_t)m * 32 + 8 * kg;
      const float* p1 = W2 + (size_t)(16 + m) * 32 + 8 * kg;
      #pragma unroll
      for (int e2 = 0; e2 < 8; ++e2) {
        w2f0[e2] = (_Float16)p0[e2];
        w2f1[e2] = (_Float16)p1[e2];
      }
    }
    // W3 A-fragment: rows padded 5 -> 16; a[e2] = W3[m][8kg+e2] (zero for m>=5)
    half8 w3f;
    #pragma unroll
    for (int e2 = 0; e2 < 8; ++e2) {
      w3f[e2] = (m < 5) ? (_Float16)W3[m * 32 + 8 * kg + e2] : (_Float16)0.f;
    }

    // W1/b1 packed pairs: neurons (8kg+2p, 8kg+2p+1)
    __half2 w1z[4], w1l[4], w1n[4], b1p[4];
    #pragma unroll
    for (int p = 0; p < 4; ++p) {
      int n0 = 8 * kg + 2 * p;
      w1z[p] = __halves2half2(__float2half(W1[n0 * 3 + 0]), __float2half(W1[n0 * 3 + 3]));
      w1l[p] = __halves2half2(__float2half(W1[n0 * 3 + 1]), __float2half(W1[n0 * 3 + 4]));
      w1n[p] = __halves2half2(__float2half(W1[n0 * 3 + 2]), __float2half(W1[n0 * 3 + 5]));
      b1p[p] = __halves2half2(__float2half(b1[n0]), __float2half(b1[n0 + 1]));
    }
    float4v b2a = *(const float4v*)(b2 + 4 * kg);
    float4v b2b = *(const float4v*)(b2 + 16 + 4 * kg);
    const float b30 = b3[0], b31 = b3[1], b32 = b3[2], b33 = b3[3], b34 = b3[4];
    const float kS = 2.0609929f;     // log2(e)/0.7

    // shuffle sources for C-layout -> B-fragment redistribution
    const int srcA = (kg & 1) * 32 + m;   // lane holding rows 8kg..8kg+3 (acc0 pair if kg<2, acc1 pair else)
    const int srcB = srcA + 16;           // lane holding rows 8kg+4..8kg+7
    const bool hiHalf = (kg >= 2);

    auto do_col = [&](int ch, int pp) {
      __half2 z2 = __half2half2(gbuf[ch][0][m][pp]);
      __half2 l2 = __half2half2(gbuf[ch][1][m][pp]);
      __half2 n2 = __half2half2(gbuf[ch][2][m][pp]);

      // layer 1 (packed pairs) + GELU -> f16 B-fragment
      union { __half2 h2[4]; half8 h8; } bu;
      #pragma unroll
      for (int p = 0; p < 4; ++p) {
        __half2 pre = __hfma2(w1z[p], z2, b1p[p]);
        pre = __hfma2(w1l[p], l2, pre);
        pre = __hfma2(w1n[p], n2, pre);
        bu.h2[p] = gelu_h2(pre);
      }

      // layer 2: single-pass f16 MFMA per g-tile
      float4v acc0 = {0.f,0.f,0.f,0.f}, acc1 = {0.f,0.f,0.f,0.f};
      acc0 = __builtin_amdgcn_mfma_f32_16x16x32_f16(w2f0, bu.h8, acc0, 0, 0, 0);
      acc1 = __builtin_amdgcn_mfma_f32_16x16x32_f16(w2f1, bu.h8, acc1, 0, 0, 0);

      // bias -> pack pairs -> packed GELU (C-layout: hh0/hh1 = rows 4kg+{01,23}; hh2/hh3 = +16)
      __half2 hh0 = __floats2half2_rn(acc0[0] + b2a[0], acc0[1] + b2a[1]);
      __half2 hh1 = __floats2half2_rn(acc0[2] + b2a[2], acc0[3] + b2a[3]);
      __half2 hh2 = __floats2half2_rn(acc1[0] + b2b[0], acc1[1] + b2b[1]);
      __half2 hh3 = __floats2half2_rn(acc1[2] + b2b[2], acc1[3] + b2b[3]);
      hh0 = gelu_h2(hh0); hh1 = gelu_h2(hh1); hh2 = gelu_h2(hh2); hh3 = gelu_h2(hh3);

      // redistribute C-layout h2 -> B-fragment rows 8kg+e2 (DEST-side hi/lo select)
      unsigned XA0 = __shfl(h2u(hh0), srcA);
      unsigned XA1 = __shfl(h2u(hh1), srcA);
      unsigned XA2 = __shfl(h2u(hh2), srcA);
      unsigned XA3 = __shfl(h2u(hh3), srcA);
      unsigned XB0 = __shfl(h2u(hh0), srcB);
      unsigned XB1 = __shfl(h2u(hh1), srcB);
      unsigned XB2 = __shfl(h2u(hh2), srcB);
      unsigned XB3 = __shfl(h2u(hh3), srcB);
      union { unsigned u[4]; half8 h8; } b2f;
      b2f.u[0] = hiHalf ? XA2 : XA0;
      b2f.u[1] = hiHalf ? XA3 : XA1;
      b2f.u[2] = hiHalf ? XB2 : XB0;
      b2f.u[3] = hiHalf ? XB3 : XB1;

      // layer 3: logits via MFMA (W3 padded 5->16 rows), f32 accum
      float4v d2 = {0.f,0.f,0.f,0.f};
      d2 = __builtin_amdgcn_mfma_f32_16x16x32_f16(w3f, b2f.h8, d2, 0, 0, 0);

      // broadcast the 5 logits of column m to all lanes
      float lg0 = __shfl(d2[0], m) + b30;
      float lg1 = __shfl(d2[1], m) + b31;
      float lg2 = __shfl(d2[2], m) + b32;
      float lg3 = __shfl(d2[3], m) + b33;
      float lg4 = __shfl(d2[0], m + 16) + b34;

      // softmax(logits/0.7), no max-sub (logits O(1) for this data)
      float e0 = fast_exp2(lg0 * kS);
      float e1 = fast_exp2(lg1 * kS);
      float e2 = fast_exp2(lg2 * kS);
      float e3 = fast_exp2(lg3 * kS);
      float e4 = fast_exp2(lg4 * kS);
      const float rs = fast_rcp(e0 + e1 + e2 + e3 + e4);

      float gw = e0;
      gw = (kg == 1) ? e1 : gw;
      gw = (kg == 2) ? e2 : gw;
      gw = (kg == 3) ? e3 : gw;
      gbuf[ch][kg][m][pp] = __float2half(gw * rs);
      if (kg == 0) gbuf[ch][4][m][pp] = __float2half(e4 * rs);
    };

    #pragma unroll 1
    for (int pp = 0; pp < 16; ++pp) {
      do_col(ch0, pp);
      do_col(ch1, pp);
    }
  }
  // gates produced & consumed by the same wave -> no barrier needed

  // ======== Phase B: Toeplitz-MFMA conv (tap-hi only, bf16) ========
  {
    const int hq = lane >> 4, p = lane & 15;
    const int ch0 = 2 * wvi, ch1 = 2 * wvi + 1;

    const int Rs[5]    = {32, 64, 128, 256, 512};
    const int steps[5] = {3, 5, 9, 17, 33};
    const int cum[5]   = {0, 3, 8, 17, 34};

    float4v o0 = {0.f,0.f,0.f,0.f}, o1 = {0.f,0.f,0.f,0.f};

    #pragma unroll 1
    for (int s = 0; s < 5; ++s) {
      float4v a0 = {0.f,0.f,0.f,0.f}, a1 = {0.f,0.f,0.f,0.f};
      const int eb0 = PAD + 256 * ch0 - Rs[s] + 16 * p + 8 * hq;
      const int eb1 = eb0 + 256;
      const unsigned short* ahb = g_afrag_hi + (size_t)cum[s] * 512 + lane * 8;

      for (int st = 0; st < steps[s]; ++st) {
        short8 kh = *(const short8*)(ahb + st * 512);
        short8 b0h = *(const short8*)(&row_hi[eb0 + st * 32]);
        short8 b1h = *(const short8*)(&row_hi[eb1 + st * 32]);
        a0 = __builtin_amdgcn_mfma_f32_16x16x32_bf16(kh, b0h, a0, 0, 0, 0);
        a1 = __builtin_amdgcn_mfma_f32_16x16x32_bf16(kh, b1h, a1, 0, 0, 0);
      }
      #pragma unroll
      for (int r = 0; r < 4; ++r) {
        o0[r] = fmaf(__half2float(gbuf[ch0][s][4 * hq + r][p]), a0[r], o0[r]);
        o1[r] = fmaf(__half2float(gbuf[ch1][s][4 * hq + r][p]), a1[r], o1[r]);
      }
    }

    if (WSPATH) {
      float* orow = outT + (size_t)(b * CC + c) * TT;
      *(float4v*)(orow + 256 * ch0 + 16 * p + 4 * hq) = o0;
      *(float4v*)(orow + 256 * ch1 + 16 * p + 4 * hq) = o1;
    } else {
      const size_t obase = (size_t)b * TT * CC + c;
      #pragma unroll
      for (int r = 0; r < 4; ++r) {
        out[obase + (size_t)(256 * ch0 + 16 * p + 4 * hq + r) * CC] = o0[r];
        out[obase + (size_t)(256 * ch1 + 16 * p + 4 * hq + r) * CC] = o1[r];
      }
    }
  }
}

extern "C" void kernel_launch(void* const* d_in, const int* in_sizes, int n_in,
                              void* d_out, int out_size, void* d_ws, size_t ws_size,
                              hipStream_t stream) {
  const float* x  = (const float*)d_in[0];
  const float* W1 = (const float*)d_in[1];
  const float* b1 = (const float*)d_in[2];
  const float* W2 = (const float*)d_in[3];
  const float* b2 = (const float*)d_in[4];
  const float* W3 = (const float*)d_in[5];
  const float* b3 = (const float*)d_in[6];
  float* outp = (float*)d_out;

  const size_t xt_bytes  = (size_t)BB * CC * TT * sizeof(unsigned short);  // 8.4 MB
  const size_t ot_bytes  = (size_t)BB * CC * TT * sizeof(float);           // 16.8 MB
  if (ws_size >= xt_bytes + ot_bytes) {
    unsigned short* xT = (unsigned short*)d_ws;
    float* outT = (float*)((char*)d_ws + xt_bytes);
    hipLaunchKernelGGL(transpose_in, dim3(BB * 32), dim3(256), 0, stream, x, xT);
    hipLaunchKernelGGL(fused_main_t<1>, dim3(BB * CC), dim3(256), 0, stream,
                       x, xT, W1, b1, W2, b2, W3, b3, outT, outp);
    hipLaunchKernelGGL(transpose_out, dim3(BB * 32), dim3(256), 0, stream, outT, outp);
  } else {
    hipLaunchKernelGGL(init_frag, dim3(8), dim3(256), 0, stream);
    hipLaunchKernelGGL(fused_main_t<0>, dim3(BB * CC), dim3(256), 0, stream,
                       x, (const unsigned short*)nullptr, W1, b1, W2, b2, W3, b3,
                       (float*)nullptr, outp);
  }
}